// Round 2
// baseline (294.583 us; speedup 1.0000x reference)
//
#include <hip/hip_runtime.h>
#include <stdint.h>

#define BATCH 2
#define SEQ 2048
#define DM 1024
#define NH 16
#define HD 64
#define QR 6
#define KVR 2
#define NTOK (BATCH*SEQ)
#define NPROJ 832  // 800 padded to 13*64

typedef __bf16 bf16x8 __attribute__((ext_vector_type(8)));
typedef float f32x4 __attribute__((ext_vector_type(4)));
typedef unsigned short us8 __attribute__((ext_vector_type(8)));

__device__ inline unsigned short f2bf(float f){
  union { float f; unsigned int u; } v; v.f = f;
  unsigned int r = (v.u + 0x7fffu + ((v.u >> 16) & 1u)) >> 16;
  return (unsigned short)r;
}

// ---- cast f32 -> bf16, 4 elems/thread ----
__global__ void cast_kernel(const float* __restrict__ in, unsigned short* __restrict__ out, int n4){
  int i = blockIdx.x*blockDim.x + threadIdx.x;
  if (i >= n4) return;
  float4 v = ((const float4*)in)[i];
  ushort4 o; o.x = f2bf(v.x); o.y = f2bf(v.y); o.z = f2bf(v.z); o.w = f2bf(v.w);
  ((ushort4*)out)[i] = o;
}

// ---- build concatenated weight (832x1024 bf16) + bias (832 f32) ----
__global__ void build_wcat(const float* __restrict__ Waq, const float* __restrict__ Wak,
                           const float* __restrict__ Wav, const float* __restrict__ Wbq,
                           const float* __restrict__ Wbk, const float* __restrict__ Wbv,
                           const float* __restrict__ baq, const float* __restrict__ bak,
                           const float* __restrict__ bav, const float* __restrict__ bbq,
                           const float* __restrict__ bbk, const float* __restrict__ bbv,
                           unsigned short* __restrict__ Wcat, float* __restrict__ bcat){
  int n = blockIdx.x; int t = threadIdx.x;
  const float* src = nullptr; float bv_ = 0.f;
  if (n < 96)       { src = Waq + (size_t)n*DM;        bv_ = baq[n]; }
  else if (n < 128) { src = Wak + (size_t)(n-96)*DM;   bv_ = bak[n-96]; }
  else if (n < 160) { src = Wav + (size_t)(n-128)*DM;  bv_ = bav[n-128]; }
  else if (n < 544) { src = Wbq + (size_t)(n-160)*DM;  bv_ = bbq[n-160]; }
  else if (n < 672) { src = Wbk + (size_t)(n-544)*DM;  bv_ = bbk[n-544]; }
  else if (n < 800) { src = Wbv + (size_t)(n-672)*DM;  bv_ = bbv[n-672]; }
  unsigned short* dst = Wcat + (size_t)n*DM;
  if (src){
    float4 v = ((const float4*)src)[t];
    ushort4 o; o.x = f2bf(v.x); o.y = f2bf(v.y); o.z = f2bf(v.z); o.w = f2bf(v.w);
    ((ushort4*)dst)[t] = o;
  } else {
    ushort4 z = {0,0,0,0};
    ((ushort4*)dst)[t] = z;
  }
  if (t == 0) bcat[n] = bv_;
}

// ---- generic NT bf16 MFMA GEMM: C[M,N] = A[M,K] * Bw[N,K]^T + bias ----
__global__ __launch_bounds__(256) void gemm_nt(const unsigned short* __restrict__ A,
    const unsigned short* __restrict__ Bw, const float* __restrict__ bias,
    float* __restrict__ C, int M, int N, int K){
  __shared__ unsigned short As[64][72];
  __shared__ unsigned short Bs[64][72];
  int tid = threadIdx.x; int w = tid >> 6; int lane = tid & 63;
  int m0 = blockIdx.x*64, n0 = blockIdx.y*64;
  f32x4 acc[4] = {};
  int lr = tid >> 3;        // 0..31
  int lc = (tid & 7)*8;     // 0..56
  int row = w*16 + (lane & 15);
  int kb  = (lane >> 4)*8;
  for (int kt = 0; kt < K; kt += 64){
    us8 a0 = *(const us8*)(A  + (size_t)(m0+lr)*K    + kt + lc);
    us8 a1 = *(const us8*)(A  + (size_t)(m0+lr+32)*K + kt + lc);
    us8 b0 = *(const us8*)(Bw + (size_t)(n0+lr)*K    + kt + lc);
    us8 b1 = *(const us8*)(Bw + (size_t)(n0+lr+32)*K + kt + lc);
    __syncthreads();
    *(us8*)&As[lr][lc] = a0;    *(us8*)&As[lr+32][lc] = a1;
    *(us8*)&Bs[lr][lc] = b0;    *(us8*)&Bs[lr+32][lc] = b1;
    __syncthreads();
    bf16x8 af0 = *(const bf16x8*)&As[row][kb];
    bf16x8 af1 = *(const bf16x8*)&As[row][32+kb];
    #pragma unroll
    for (int nf = 0; nf < 4; ++nf){
      int col = nf*16 + (lane & 15);
      bf16x8 bf0 = *(const bf16x8*)&Bs[col][kb];
      bf16x8 bf1 = *(const bf16x8*)&Bs[col][32+kb];
      acc[nf] = __builtin_amdgcn_mfma_f32_16x16x32_bf16(af0, bf0, acc[nf], 0,0,0);
      acc[nf] = __builtin_amdgcn_mfma_f32_16x16x32_bf16(af1, bf1, acc[nf], 0,0,0);
    }
  }
  int rbase = w*16 + (lane >> 4)*4;
  #pragma unroll
  for (int nf = 0; nf < 4; ++nf){
    int col = n0 + nf*16 + (lane & 15);
    float bv_ = bias ? bias[col] : 0.f;
    #pragma unroll
    for (int r = 0; r < 4; ++r){
      C[(size_t)(m0 + rbase + r)*N + col] = acc[nf][r] + bv_;
    }
  }
}

// ---- RoPE + rank contraction: build Q,K,V (B,H,S,D) bf16; 1/8 folded into Q ----
__global__ __launch_bounds__(256) void qkv_kernel(const float* __restrict__ proj,
    const float* __restrict__ cosT, const float* __restrict__ sinT,
    unsigned short* __restrict__ Q, unsigned short* __restrict__ K,
    unsigned short* __restrict__ V){
  int token = blockIdx.x; int b = token >> 11; int s = token & 2047;
  const float* row = proj + (size_t)token*NPROJ;
  __shared__ float aq[96], ak[32], av[32], bq[QR][HD], bk[KVR][HD], bv[KVR][HD];
  int t = threadIdx.x;
  for (int i = t; i < 800; i += 256){
    float vv = row[i];
    if (i < 96) aq[i] = vv;
    else if (i < 128) ak[i-96] = vv;
    else if (i < 160) av[i-128] = vv;
    else if (i < 544) (&bq[0][0])[i-160] = vv;
    else if (i < 672) (&bk[0][0])[i-544] = vv;
    else (&bv[0][0])[i-672] = vv;
  }
  __syncthreads();
  {
    if (t < 192){
      int r = t >> 5, i = t & 31;
      float c = cosT[s*32+i], sn = sinT[s*32+i];
      float x1 = bq[r][2*i], x2 = bq[r][2*i+1];
      bq[r][2*i]   = x1*c - x2*sn;
      bq[r][2*i+1] = x1*sn + x2*c;
    } else {
      int r = (t-192) >> 5, i = t & 31;
      float c = cosT[s*32+i], sn = sinT[s*32+i];
      float x1 = bk[r][2*i], x2 = bk[r][2*i+1];
      bk[r][2*i]   = x1*c - x2*sn;
      bk[r][2*i+1] = x1*sn + x2*c;
    }
  }
  __syncthreads();
  int h = t >> 4; int dbase = (t & 15)*4;
  float qv[4] = {}, kv[4] = {}, vv[4] = {};
  #pragma unroll
  for (int r = 0; r < QR; ++r){
    float a = aq[h*QR + r];
    #pragma unroll
    for (int j = 0; j < 4; ++j) qv[j] += a * bq[r][dbase+j];
  }
  #pragma unroll
  for (int r = 0; r < KVR; ++r){
    float a1 = ak[h*KVR + r], a2 = av[h*KVR + r];
    #pragma unroll
    for (int j = 0; j < 4; ++j){ kv[j] += a1 * bk[r][dbase+j]; vv[j] += a2 * bv[r][dbase+j]; }
  }
  size_t base = ((size_t)(b*NH + h)*SEQ + s)*HD + dbase;
  ushort4 qo; qo.x=f2bf(qv[0]*0.125f); qo.y=f2bf(qv[1]*0.125f); qo.z=f2bf(qv[2]*0.125f); qo.w=f2bf(qv[3]*0.125f);
  ushort4 ko; ko.x=f2bf(kv[0]); ko.y=f2bf(kv[1]); ko.z=f2bf(kv[2]); ko.w=f2bf(kv[3]);
  ushort4 vo; vo.x=f2bf(vv[0]); vo.y=f2bf(vv[1]); vo.z=f2bf(vv[2]); vo.w=f2bf(vv[3]);
  *(ushort4*)(Q+base) = qo;
  *(ushort4*)(K+base) = ko;
  *(ushort4*)(V+base) = vo;
}

// ---- causal flash attention, barrier-free: 1 wave = 16 q-rows, KVBLK=32.
// grid: 1024 blocks x 256 thr (4 independent waves). K frags straight from
// global (L2-hot, XCD-pinned per bh); V transposed + P staged in per-wave LDS.
__global__ __launch_bounds__(256) void attn_kernel(const unsigned short* __restrict__ Q,
   const unsigned short* __restrict__ K, const unsigned short* __restrict__ V,
   unsigned short* __restrict__ attnOut){
  __shared__ unsigned short Vt[4][64][34];
  __shared__ unsigned short Pw[4][16][34];
  int tid = threadIdx.x, w = tid >> 6, lane = tid & 63;
  int id = blockIdx.x;
  int xcd = id & 7, slot = id >> 3;          // pin 4 bh per XCD for L2 residency
  int bh  = xcd*4 + (slot >> 5);
  int qt  = (31 - (slot & 31))*4 + w;        // heavy q-tiles dispatched first
  int b = bh >> 4, h = bh & 15;
  const unsigned short* Qp = Q + (size_t)bh*SEQ*HD;
  const unsigned short* Kp = K + (size_t)bh*SEQ*HD;
  const unsigned short* Vp = V + (size_t)bh*SEQ*HD;
  int l15 = lane & 15, lg = lane >> 4;
  int kb = lg*8;
  int qrow = qt*16 + l15;
  bf16x8 aq0 = *(const bf16x8*)(Qp + (size_t)qrow*HD + kb);
  bf16x8 aq1 = *(const bf16x8*)(Qp + (size_t)qrow*HD + 32 + kb);
  float m[4], l[4]; f32x4 o[4] = {};
  #pragma unroll
  for (int r = 0; r < 4; ++r){ m[r] = -1e30f; l[r] = 0.f; }
  int ntile = (qt >> 1) + 1;
  int sv = lane & 31, c4 = (lane >> 5)*8;    // V staging: lane -> (k=sv, d=c4+c*16..)
  for (int t = 0; t < ntile; ++t){
    int k0 = t*32;
    // V tile load (issue early; longest latency)
    const unsigned short* Vbp = Vp + (size_t)(k0+sv)*HD + c4;
    us8 v0 = *(const us8*)(Vbp);
    us8 v1 = *(const us8*)(Vbp+16);
    us8 v2 = *(const us8*)(Vbp+32);
    us8 v3 = *(const us8*)(Vbp+48);
    // K frags straight from global (row-major NT addressing, cancels with Q frag)
    bf16x8 bk00 = *(const bf16x8*)(Kp + (size_t)(k0 +      l15)*HD + kb);
    bf16x8 bk01 = *(const bf16x8*)(Kp + (size_t)(k0 +      l15)*HD + 32 + kb);
    bf16x8 bk10 = *(const bf16x8*)(Kp + (size_t)(k0 + 16 + l15)*HD + kb);
    bf16x8 bk11 = *(const bf16x8*)(Kp + (size_t)(k0 + 16 + l15)*HD + 32 + kb);
    f32x4 sf0 = {}, sf1 = {};
    sf0 = __builtin_amdgcn_mfma_f32_16x16x32_bf16(aq0, bk00, sf0, 0,0,0);
    sf0 = __builtin_amdgcn_mfma_f32_16x16x32_bf16(aq1, bk01, sf0, 0,0,0);
    sf1 = __builtin_amdgcn_mfma_f32_16x16x32_bf16(aq0, bk10, sf1, 0,0,0);
    sf1 = __builtin_amdgcn_mfma_f32_16x16x32_bf16(aq1, bk11, sf1, 0,0,0);
    // V transpose into private LDS (in-order DS pipe; no barrier needed)
    #pragma unroll
    for (int j = 0; j < 8; ++j){
      Vt[w][c4 +      j][sv] = v0[j];
      Vt[w][c4 + 16 + j][sv] = v1[j];
      Vt[w][c4 + 32 + j][sv] = v2[j];
      Vt[w][c4 + 48 + j][sv] = v3[j];
    }
    bool lastt = (t == ntile-1);   // only the final tile crosses the diagonal
    float p0a[4], p1a[4];
    #pragma unroll
    for (int r = 0; r < 4; ++r){
      float s0 = sf0[r], s1 = sf1[r];
      if (lastt){
        int grow = qt*16 + lg*4 + r;
        s0 = (k0 +      l15) <= grow ? s0 : -1e30f;
        s1 = (k0 + 16 + l15) <= grow ? s1 : -1e30f;
      }
      float cmax = fmaxf(s0, s1);
      cmax = fmaxf(cmax, __shfl_xor(cmax, 1));
      cmax = fmaxf(cmax, __shfl_xor(cmax, 2));
      cmax = fmaxf(cmax, __shfl_xor(cmax, 4));
      cmax = fmaxf(cmax, __shfl_xor(cmax, 8));
      float mn = fmaxf(m[r], cmax);
      float alpha = __expf(m[r] - mn);
      float p0 = __expf(s0 - mn), p1 = __expf(s1 - mn);
      float rs = p0 + p1;
      rs += __shfl_xor(rs, 1); rs += __shfl_xor(rs, 2);
      rs += __shfl_xor(rs, 4); rs += __shfl_xor(rs, 8);
      l[r] = l[r]*alpha + rs;
      m[r] = mn;
      o[0][r] *= alpha; o[1][r] *= alpha; o[2][r] *= alpha; o[3][r] *= alpha;
      p0a[r] = p0; p1a[r] = p1;
    }
    #pragma unroll
    for (int r = 0; r < 4; ++r){
      Pw[w][lg*4 + r][     l15] = f2bf(p0a[r]);
      Pw[w][lg*4 + r][16 + l15] = f2bf(p1a[r]);
    }
    bf16x8 pf = *(const bf16x8*)&Pw[w][l15][kb];
    #pragma unroll
    for (int nd = 0; nd < 4; ++nd){
      bf16x8 vf = *(const bf16x8*)&Vt[w][nd*16 + l15][kb];
      o[nd] = __builtin_amdgcn_mfma_f32_16x16x32_bf16(pf, vf, o[nd], 0,0,0);
    }
  }
  int srow = qt*16 + lg*4;
  #pragma unroll
  for (int nd = 0; nd < 4; ++nd){
    int col = h*HD + nd*16 + l15;
    #pragma unroll
    for (int r = 0; r < 4; ++r){
      float val = o[nd][r] / l[r];
      attnOut[((size_t)b*SEQ + (srow + r))*DM + col] = f2bf(val);
    }
  }
}

extern "C" void kernel_launch(void* const* d_in, const int* in_sizes, int n_in,
                              void* d_out, int out_size, void* d_ws, size_t ws_size,
                              hipStream_t stream){
  const float* x   = (const float*)d_in[0];
  const float* Waq = (const float*)d_in[1];
  const float* baq = (const float*)d_in[2];
  const float* Wbq = (const float*)d_in[3];
  const float* bbq = (const float*)d_in[4];
  const float* Wak = (const float*)d_in[5];
  const float* bak = (const float*)d_in[6];
  const float* Wbk = (const float*)d_in[7];
  const float* bbk = (const float*)d_in[8];
  const float* Wav = (const float*)d_in[9];
  const float* bav = (const float*)d_in[10];
  const float* Wbv = (const float*)d_in[11];
  const float* bbv = (const float*)d_in[12];
  const float* Wo  = (const float*)d_in[13];
  const float* bo  = (const float*)d_in[14];
  const float* cosT= (const float*)d_in[15];
  const float* sinT= (const float*)d_in[16];
  float* out = (float*)d_out;

  char* ws = (char*)d_ws;
  unsigned short* xb    = (unsigned short*)(ws + 0);          // 8.4 MB
  unsigned short* Wob   = (unsigned short*)(ws + 8388608);    // 2.1 MB
  unsigned short* Wcat  = (unsigned short*)(ws + 10485760);   // 1.7 MB
  float*          bcat  = (float*)(ws + 12189696);            // 3.3 KB
  float*          proj  = (float*)(ws + 12193280);            // 13.6 MB
  unsigned short* Qb    = (unsigned short*)(ws + 25824768);   // 8.4 MB
  unsigned short* Kb    = (unsigned short*)(ws + 34213376);   // 8.4 MB
  unsigned short* Vb    = (unsigned short*)(ws + 42601984);   // 8.4 MB
  unsigned short* attnB = (unsigned short*)(ws + 50990592);   // 8.4 MB

  cast_kernel<<<4096, 256, 0, stream>>>(x, xb, 1048576);
  cast_kernel<<<1024, 256, 0, stream>>>(Wo, Wob, 262144);
  build_wcat<<<832, 256, 0, stream>>>(Waq, Wak, Wav, Wbq, Wbk, Wbv,
                                      baq, bak, bav, bbq, bbk, bbv, Wcat, bcat);
  gemm_nt<<<dim3(64,13), 256, 0, stream>>>(xb, Wcat, bcat, proj, NTOK, NPROJ, DM);
  qkv_kernel<<<4096, 256, 0, stream>>>(proj, cosT, sinT, Qb, Kb, Vb);
  attn_kernel<<<1024, 256, 0, stream>>>(Qb, Kb, Vb, attnB);
  gemm_nt<<<dim3(64,16), 256, 0, stream>>>(attnB, Wob, bo, out, NTOK, DM, DM);
}

// Round 3
// 135.843 us; speedup vs baseline: 2.1685x; 2.1685x over previous
//
#include <hip/hip_runtime.h>
#include <stdint.h>

#define BATCH 2
#define SEQ 2048
#define DM 1024
#define NH 16
#define HD 64
#define QR 6
#define KVR 2
#define NTOK (BATCH*SEQ)
#define NPROJ 832  // 800 padded to 13*64

typedef __bf16 bf16x8 __attribute__((ext_vector_type(8)));
typedef float f32x4 __attribute__((ext_vector_type(4)));
typedef unsigned short us8 __attribute__((ext_vector_type(8)));

__device__ inline unsigned short f2bf(float f){
  union { float f; unsigned int u; } v; v.f = f;
  unsigned int r = (v.u + 0x7fffu + ((v.u >> 16) & 1u)) >> 16;
  return (unsigned short)r;
}

// ---- cast f32 -> bf16, 4 elems/thread ----
__global__ void cast_kernel(const float* __restrict__ in, unsigned short* __restrict__ out, int n4){
  int i = blockIdx.x*blockDim.x + threadIdx.x;
  if (i >= n4) return;
  float4 v = ((const float4*)in)[i];
  ushort4 o; o.x = f2bf(v.x); o.y = f2bf(v.y); o.z = f2bf(v.z); o.w = f2bf(v.w);
  ((ushort4*)out)[i] = o;
}

// ---- build concatenated weight (832x1024 bf16) + bias (832 f32) ----
__global__ void build_wcat(const float* __restrict__ Waq, const float* __restrict__ Wak,
                           const float* __restrict__ Wav, const float* __restrict__ Wbq,
                           const float* __restrict__ Wbk, const float* __restrict__ Wbv,
                           const float* __restrict__ baq, const float* __restrict__ bak,
                           const float* __restrict__ bav, const float* __restrict__ bbq,
                           const float* __restrict__ bbk, const float* __restrict__ bbv,
                           unsigned short* __restrict__ Wcat, float* __restrict__ bcat){
  int n = blockIdx.x; int t = threadIdx.x;
  const float* src = nullptr; float bv_ = 0.f;
  if (n < 96)       { src = Waq + (size_t)n*DM;        bv_ = baq[n]; }
  else if (n < 128) { src = Wak + (size_t)(n-96)*DM;   bv_ = bak[n-96]; }
  else if (n < 160) { src = Wav + (size_t)(n-128)*DM;  bv_ = bav[n-128]; }
  else if (n < 544) { src = Wbq + (size_t)(n-160)*DM;  bv_ = bbq[n-160]; }
  else if (n < 672) { src = Wbk + (size_t)(n-544)*DM;  bv_ = bbk[n-544]; }
  else if (n < 800) { src = Wbv + (size_t)(n-672)*DM;  bv_ = bbv[n-672]; }
  unsigned short* dst = Wcat + (size_t)n*DM;
  if (src){
    float4 v = ((const float4*)src)[t];
    ushort4 o; o.x = f2bf(v.x); o.y = f2bf(v.y); o.z = f2bf(v.z); o.w = f2bf(v.w);
    ((ushort4*)dst)[t] = o;
  } else {
    ushort4 z = {0,0,0,0};
    ((ushort4*)dst)[t] = z;
  }
  if (t == 0) bcat[n] = bv_;
}

// ---- generic NT bf16 MFMA GEMM: C[M,N] = A[M,K] * Bw[N,K]^T + bias ----
__global__ __launch_bounds__(256) void gemm_nt(const unsigned short* __restrict__ A,
    const unsigned short* __restrict__ Bw, const float* __restrict__ bias,
    float* __restrict__ C, int M, int N, int K){
  __shared__ unsigned short As[64][72];
  __shared__ unsigned short Bs[64][72];
  int tid = threadIdx.x; int w = tid >> 6; int lane = tid & 63;
  int m0 = blockIdx.x*64, n0 = blockIdx.y*64;
  f32x4 acc[4] = {};
  int lr = tid >> 3;        // 0..31
  int lc = (tid & 7)*8;     // 0..56
  int row = w*16 + (lane & 15);
  int kb  = (lane >> 4)*8;
  for (int kt = 0; kt < K; kt += 64){
    us8 a0 = *(const us8*)(A  + (size_t)(m0+lr)*K    + kt + lc);
    us8 a1 = *(const us8*)(A  + (size_t)(m0+lr+32)*K + kt + lc);
    us8 b0 = *(const us8*)(Bw + (size_t)(n0+lr)*K    + kt + lc);
    us8 b1 = *(const us8*)(Bw + (size_t)(n0+lr+32)*K + kt + lc);
    __syncthreads();
    *(us8*)&As[lr][lc] = a0;    *(us8*)&As[lr+32][lc] = a1;
    *(us8*)&Bs[lr][lc] = b0;    *(us8*)&Bs[lr+32][lc] = b1;
    __syncthreads();
    bf16x8 af0 = *(const bf16x8*)&As[row][kb];
    bf16x8 af1 = *(const bf16x8*)&As[row][32+kb];
    #pragma unroll
    for (int nf = 0; nf < 4; ++nf){
      int col = nf*16 + (lane & 15);
      bf16x8 bf0 = *(const bf16x8*)&Bs[col][kb];
      bf16x8 bf1 = *(const bf16x8*)&Bs[col][32+kb];
      acc[nf] = __builtin_amdgcn_mfma_f32_16x16x32_bf16(af0, bf0, acc[nf], 0,0,0);
      acc[nf] = __builtin_amdgcn_mfma_f32_16x16x32_bf16(af1, bf1, acc[nf], 0,0,0);
    }
  }
  int rbase = w*16 + (lane >> 4)*4;
  #pragma unroll
  for (int nf = 0; nf < 4; ++nf){
    int col = n0 + nf*16 + (lane & 15);
    float bv_ = bias ? bias[col] : 0.f;
    #pragma unroll
    for (int r = 0; r < 4; ++r){
      C[(size_t)(m0 + rbase + r)*N + col] = acc[nf][r] + bv_;
    }
  }
}

// ---- RoPE + rank contraction: build Q,K,V (B,H,S,D) bf16.
// Q folds 1/sqrt(64)/ln2 so attention can use exp2. ----
__global__ __launch_bounds__(256) void qkv_kernel(const float* __restrict__ proj,
    const float* __restrict__ cosT, const float* __restrict__ sinT,
    unsigned short* __restrict__ Q, unsigned short* __restrict__ K,
    unsigned short* __restrict__ V){
  int token = blockIdx.x; int b = token >> 11; int s = token & 2047;
  const float* row = proj + (size_t)token*NPROJ;
  __shared__ float aq[96], ak[32], av[32], bq[QR][HD], bk[KVR][HD], bv[KVR][HD];
  int t = threadIdx.x;
  for (int i = t; i < 800; i += 256){
    float vv = row[i];
    if (i < 96) aq[i] = vv;
    else if (i < 128) ak[i-96] = vv;
    else if (i < 160) av[i-128] = vv;
    else if (i < 544) (&bq[0][0])[i-160] = vv;
    else if (i < 672) (&bk[0][0])[i-544] = vv;
    else (&bv[0][0])[i-672] = vv;
  }
  __syncthreads();
  {
    if (t < 192){
      int r = t >> 5, i = t & 31;
      float c = cosT[s*32+i], sn = sinT[s*32+i];
      float x1 = bq[r][2*i], x2 = bq[r][2*i+1];
      bq[r][2*i]   = x1*c - x2*sn;
      bq[r][2*i+1] = x1*sn + x2*c;
    } else {
      int r = (t-192) >> 5, i = t & 31;
      float c = cosT[s*32+i], sn = sinT[s*32+i];
      float x1 = bk[r][2*i], x2 = bk[r][2*i+1];
      bk[r][2*i]   = x1*c - x2*sn;
      bk[r][2*i+1] = x1*sn + x2*c;
    }
  }
  __syncthreads();
  int h = t >> 4; int dbase = (t & 15)*4;
  float qv[4] = {}, kv[4] = {}, vv[4] = {};
  #pragma unroll
  for (int r = 0; r < QR; ++r){
    float a = aq[h*QR + r];
    #pragma unroll
    for (int j = 0; j < 4; ++j) qv[j] += a * bq[r][dbase+j];
  }
  #pragma unroll
  for (int r = 0; r < KVR; ++r){
    float a1 = ak[h*KVR + r], a2 = av[h*KVR + r];
    #pragma unroll
    for (int j = 0; j < 4; ++j){ kv[j] += a1 * bk[r][dbase+j]; vv[j] += a2 * bv[r][dbase+j]; }
  }
  size_t base = ((size_t)(b*NH + h)*SEQ + s)*HD + dbase;
  const float QS = 0.18033688f;  // 0.125 / ln(2)
  ushort4 qo; qo.x=f2bf(qv[0]*QS); qo.y=f2bf(qv[1]*QS); qo.z=f2bf(qv[2]*QS); qo.w=f2bf(qv[3]*QS);
  ushort4 ko; ko.x=f2bf(kv[0]); ko.y=f2bf(kv[1]); ko.z=f2bf(kv[2]); ko.w=f2bf(kv[3]);
  ushort4 vo; vo.x=f2bf(vv[0]); vo.y=f2bf(vv[1]); vo.z=f2bf(vv[2]); vo.w=f2bf(vv[3]);
  *(ushort4*)(Q+base) = qo;
  *(ushort4*)(K+base) = ko;
  *(ushort4*)(V+base) = vo;
}

// ---- one-shot V transpose: V[bh][s][d] -> VT[bh][d][s] ----
__global__ __launch_bounds__(256) void transpose_v(const unsigned short* __restrict__ V,
    unsigned short* __restrict__ VT){
  __shared__ unsigned short tile[64][72];
  int bh = blockIdx.y; int s0 = blockIdx.x*64;
  int tid = threadIdx.x;
  int r = tid >> 3, c = (tid & 7)*8;
  const unsigned short* src = V + ((size_t)bh*SEQ + s0)*HD;
  *(us8*)&tile[r][c]    = *(const us8*)(src + (size_t)r*HD + c);
  *(us8*)&tile[r+32][c] = *(const us8*)(src + (size_t)(r+32)*HD + c);
  __syncthreads();
  unsigned short* dst = VT + (size_t)bh*HD*SEQ + s0;
  us8 o0, o1;
  #pragma unroll
  for (int j = 0; j < 8; ++j){ o0[j] = tile[c+j][r]; o1[j] = tile[c+j][r+32]; }
  *(us8*)(dst + (size_t)r*SEQ + c)      = o0;
  *(us8*)(dst + (size_t)(r+32)*SEQ + c) = o1;
}

// ---- causal flash attention: 64 q-rows/block (4 waves x 16), KVBLK=64,
// double-buffered LDS staging with cross-tile prefetch, 1 barrier/tile.
__global__ __launch_bounds__(256) void attn_kernel(const unsigned short* __restrict__ Q,
   const unsigned short* __restrict__ K, const unsigned short* __restrict__ VT,
   unsigned short* __restrict__ attnOut){
  __shared__ unsigned short Ks[2][64][72];
  __shared__ unsigned short Vs[2][64][72];   // transposed: [d][k]
  __shared__ unsigned short Pw[4][16][72];
  int tid = threadIdx.x, w = tid >> 6, lane = tid & 63;
  int id = blockIdx.x;
  int xcd = id & 7, slot = id >> 3;          // 4 bh per XCD -> K/V L2-resident
  int bh  = xcd*4 + (slot & 3);
  int qblk = 31 - (slot >> 2);               // heavy q-tiles first
  int b = bh >> 4, h = bh & 15;
  const unsigned short* Qp = Q  + (size_t)bh*SEQ*HD;
  const unsigned short* Kp = K  + (size_t)bh*SEQ*HD;
  const unsigned short* Vp = VT + (size_t)bh*HD*SEQ;
  int l15 = lane & 15, lg = lane >> 4;
  int kb = lg*8;
  int qrow = qblk*64 + w*16 + l15;
  bf16x8 aq0 = *(const bf16x8*)(Qp + (size_t)qrow*HD + kb);
  bf16x8 aq1 = *(const bf16x8*)(Qp + (size_t)qrow*HD + 32 + kb);
  float m[4], l[4]; f32x4 o[4] = {};
  #pragma unroll
  for (int r = 0; r < 4; ++r){ m[r] = -1e30f; l[r] = 0.f; }
  int ntile = qblk + 1;
  int lr = tid >> 3, lc = (tid & 7)*8;       // staging: rows lr,lr+32 x col lc
  // prologue: tile 0 into regs
  us8 cka = *(const us8*)(Kp + (size_t)lr*HD + lc);
  us8 ckb = *(const us8*)(Kp + (size_t)(lr+32)*HD + lc);
  us8 cva = *(const us8*)(Vp + (size_t)lr*SEQ + lc);
  us8 cvb = *(const us8*)(Vp + (size_t)(lr+32)*SEQ + lc);
  for (int t = 0; t < ntile; ++t){
    int buf = t & 1;
    *(us8*)&Ks[buf][lr][lc]    = cka;
    *(us8*)&Ks[buf][lr+32][lc] = ckb;
    *(us8*)&Vs[buf][lr][lc]    = cva;
    *(us8*)&Vs[buf][lr+32][lc] = cvb;
    if (t + 1 < ntile){                      // prefetch next tile (latency hides
      int k1 = (t+1)*64;                     // under barrier + this tile's compute)
      cka = *(const us8*)(Kp + (size_t)(k1+lr)*HD + lc);
      ckb = *(const us8*)(Kp + (size_t)(k1+lr+32)*HD + lc);
      cva = *(const us8*)(Vp + (size_t)lr*SEQ + k1 + lc);
      cvb = *(const us8*)(Vp + (size_t)(lr+32)*SEQ + k1 + lc);
    }
    __syncthreads();
    // QK^T: 16 q-rows x 64 k-cols
    f32x4 sf[4] = {};
    #pragma unroll
    for (int nf = 0; nf < 4; ++nf){
      bf16x8 b0 = *(const bf16x8*)&Ks[buf][nf*16 + l15][kb];
      bf16x8 b1 = *(const bf16x8*)&Ks[buf][nf*16 + l15][32 + kb];
      sf[nf] = __builtin_amdgcn_mfma_f32_16x16x32_bf16(aq0, b0, sf[nf], 0,0,0);
      sf[nf] = __builtin_amdgcn_mfma_f32_16x16x32_bf16(aq1, b1, sf[nf], 0,0,0);
    }
    bool lastt = (t == qblk);                // only diagonal tile crosses mask
    float p[4][4];
    #pragma unroll
    for (int r = 0; r < 4; ++r){
      float s0 = sf[0][r], s1 = sf[1][r], s2 = sf[2][r], s3 = sf[3][r];
      if (lastt){
        int grow = w*16 + lg*4 + r;          // local row vs local col
        s0 = (     l15) <= grow ? s0 : -1e30f;
        s1 = (16 + l15) <= grow ? s1 : -1e30f;
        s2 = (32 + l15) <= grow ? s2 : -1e30f;
        s3 = (48 + l15) <= grow ? s3 : -1e30f;
      }
      float cmax = fmaxf(fmaxf(s0, s1), fmaxf(s2, s3));
      cmax = fmaxf(cmax, __shfl_xor(cmax, 1));
      cmax = fmaxf(cmax, __shfl_xor(cmax, 2));
      cmax = fmaxf(cmax, __shfl_xor(cmax, 4));
      cmax = fmaxf(cmax, __shfl_xor(cmax, 8));
      float mn = fmaxf(m[r], cmax);
      float alpha = exp2f(m[r] - mn);
      float p0 = exp2f(s0 - mn), p1 = exp2f(s1 - mn);
      float p2 = exp2f(s2 - mn), p3 = exp2f(s3 - mn);
      float rs = (p0 + p1) + (p2 + p3);
      rs += __shfl_xor(rs, 1); rs += __shfl_xor(rs, 2);
      rs += __shfl_xor(rs, 4); rs += __shfl_xor(rs, 8);
      l[r] = l[r]*alpha + rs;
      m[r] = mn;
      o[0][r] *= alpha; o[1][r] *= alpha; o[2][r] *= alpha; o[3][r] *= alpha;
      p[0][r] = p0; p[1][r] = p1; p[2][r] = p2; p[3][r] = p3;
    }
    #pragma unroll
    for (int r = 0; r < 4; ++r){
      __bf16* pr = (__bf16*)&Pw[w][lg*4 + r][0];
      pr[     l15] = (__bf16)p[0][r];
      pr[16 + l15] = (__bf16)p[1][r];
      pr[32 + l15] = (__bf16)p[2][r];
      pr[48 + l15] = (__bf16)p[3][r];
    }
    bf16x8 pf0 = *(const bf16x8*)&Pw[w][l15][kb];
    bf16x8 pf1 = *(const bf16x8*)&Pw[w][l15][32 + kb];
    #pragma unroll
    for (int nd = 0; nd < 4; ++nd){
      bf16x8 vf0 = *(const bf16x8*)&Vs[buf][nd*16 + l15][kb];
      bf16x8 vf1 = *(const bf16x8*)&Vs[buf][nd*16 + l15][32 + kb];
      o[nd] = __builtin_amdgcn_mfma_f32_16x16x32_bf16(pf0, vf0, o[nd], 0,0,0);
      o[nd] = __builtin_amdgcn_mfma_f32_16x16x32_bf16(pf1, vf1, o[nd], 0,0,0);
    }
  }
  int srow = qblk*64 + w*16 + lg*4;
  #pragma unroll
  for (int nd = 0; nd < 4; ++nd){
    int col = h*HD + nd*16 + l15;
    #pragma unroll
    for (int r = 0; r < 4; ++r){
      float val = o[nd][r] / l[r];
      attnOut[((size_t)b*SEQ + (srow + r))*DM + col] = f2bf(val);
    }
  }
}

extern "C" void kernel_launch(void* const* d_in, const int* in_sizes, int n_in,
                              void* d_out, int out_size, void* d_ws, size_t ws_size,
                              hipStream_t stream){
  const float* x   = (const float*)d_in[0];
  const float* Waq = (const float*)d_in[1];
  const float* baq = (const float*)d_in[2];
  const float* Wbq = (const float*)d_in[3];
  const float* bbq = (const float*)d_in[4];
  const float* Wak = (const float*)d_in[5];
  const float* bak = (const float*)d_in[6];
  const float* Wbk = (const float*)d_in[7];
  const float* bbk = (const float*)d_in[8];
  const float* Wav = (const float*)d_in[9];
  const float* bav = (const float*)d_in[10];
  const float* Wbv = (const float*)d_in[11];
  const float* bbv = (const float*)d_in[12];
  const float* Wo  = (const float*)d_in[13];
  const float* bo  = (const float*)d_in[14];
  const float* cosT= (const float*)d_in[15];
  const float* sinT= (const float*)d_in[16];
  float* out = (float*)d_out;

  char* ws = (char*)d_ws;
  unsigned short* xb    = (unsigned short*)(ws + 0);          // 8.4 MB
  unsigned short* Wob   = (unsigned short*)(ws + 8388608);    // 2.1 MB
  unsigned short* Wcat  = (unsigned short*)(ws + 10485760);   // 1.7 MB
  float*          bcat  = (float*)(ws + 12189696);            // 3.3 KB
  float*          proj  = (float*)(ws + 12193280);            // 13.6 MB
  unsigned short* Qb    = (unsigned short*)(ws + 25824768);   // 8.4 MB
  unsigned short* Kb    = (unsigned short*)(ws + 34213376);   // 8.4 MB
  unsigned short* Vb    = (unsigned short*)(ws + 42601984);   // 8.4 MB
  unsigned short* attnB = (unsigned short*)(ws + 50990592);   // 8.4 MB
  unsigned short* VTb   = (unsigned short*)(ws + 59379200);   // 8.4 MB

  cast_kernel<<<4096, 256, 0, stream>>>(x, xb, 1048576);
  cast_kernel<<<1024, 256, 0, stream>>>(Wo, Wob, 262144);
  build_wcat<<<832, 256, 0, stream>>>(Waq, Wak, Wav, Wbq, Wbk, Wbv,
                                      baq, bak, bav, bbq, bbk, bbv, Wcat, bcat);
  gemm_nt<<<dim3(64,13), 256, 0, stream>>>(xb, Wcat, bcat, proj, NTOK, NPROJ, DM);
  qkv_kernel<<<4096, 256, 0, stream>>>(proj, cosT, sinT, Qb, Kb, Vb);
  transpose_v<<<dim3(32,32), 256, 0, stream>>>(Vb, VTb);
  attn_kernel<<<1024, 256, 0, stream>>>(Qb, Kb, VTb, attnB);
  gemm_nt<<<dim3(64,16), 256, 0, stream>>>(attnB, Wob, bo, out, NTOK, DM, DM);
}

// Round 4
// 113.104 us; speedup vs baseline: 2.6045x; 1.2010x over previous
//
#include <hip/hip_runtime.h>
#include <stdint.h>

#define BATCH 2
#define SEQ 2048
#define DM 1024
#define NH 16
#define HD 64
#define QR 6
#define KVR 2
#define NTOK (BATCH*SEQ)
#define NPROJ 832    // live projection outputs
#define NPROJP 896   // padded to 7*128 for 128-tile GEMM

typedef __bf16 bf16x8 __attribute__((ext_vector_type(8)));
typedef float f32x4 __attribute__((ext_vector_type(4)));
typedef unsigned short us8 __attribute__((ext_vector_type(8)));

__device__ inline unsigned short f2bf(float f){
  union { float f; unsigned int u; } v; v.f = f;
  unsigned int r = (v.u + 0x7fffu + ((v.u >> 16) & 1u)) >> 16;
  return (unsigned short)r;
}
__device__ inline unsigned int pkbf(float a, float b){
  return (unsigned int)f2bf(a) | ((unsigned int)f2bf(b) << 16);
}

// ---- cast f32 -> bf16, 4 elems/thread ----
__global__ void cast_kernel(const float* __restrict__ in, unsigned short* __restrict__ out, int n4){
  int i = blockIdx.x*blockDim.x + threadIdx.x;
  if (i >= n4) return;
  float4 v = ((const float4*)in)[i];
  ushort4 o; o.x = f2bf(v.x); o.y = f2bf(v.y); o.z = f2bf(v.z); o.w = f2bf(v.w);
  ((ushort4*)out)[i] = o;
}

// ---- build concatenated weight (896x1024 bf16, zero-padded) + bias ----
__global__ void build_wcat(const float* __restrict__ Waq, const float* __restrict__ Wak,
                           const float* __restrict__ Wav, const float* __restrict__ Wbq,
                           const float* __restrict__ Wbk, const float* __restrict__ Wbv,
                           const float* __restrict__ baq, const float* __restrict__ bak,
                           const float* __restrict__ bav, const float* __restrict__ bbq,
                           const float* __restrict__ bbk, const float* __restrict__ bbv,
                           unsigned short* __restrict__ Wcat, float* __restrict__ bcat){
  int n = blockIdx.x; int t = threadIdx.x;
  const float* src = nullptr; float bv_ = 0.f;
  if (n < 96)       { src = Waq + (size_t)n*DM;        bv_ = baq[n]; }
  else if (n < 128) { src = Wak + (size_t)(n-96)*DM;   bv_ = bak[n-96]; }
  else if (n < 160) { src = Wav + (size_t)(n-128)*DM;  bv_ = bav[n-128]; }
  else if (n < 544) { src = Wbq + (size_t)(n-160)*DM;  bv_ = bbq[n-160]; }
  else if (n < 672) { src = Wbk + (size_t)(n-544)*DM;  bv_ = bbk[n-544]; }
  else if (n < 800) { src = Wbv + (size_t)(n-672)*DM;  bv_ = bbv[n-672]; }
  unsigned short* dst = Wcat + (size_t)n*DM;
  if (src){
    float4 v = ((const float4*)src)[t];
    ushort4 o; o.x = f2bf(v.x); o.y = f2bf(v.y); o.z = f2bf(v.z); o.w = f2bf(v.w);
    ((ushort4*)dst)[t] = o;
  } else {
    ushort4 z = {0,0,0,0};
    ((ushort4*)dst)[t] = z;
  }
  if (t == 0) bcat[n] = bv_;
}

// ---- 128x128-tile NT bf16 GEMM: C[M,N] = A[M,K]*Bw[N,K]^T + bias.
// 256 thr = 4 waves, each wave a 64x64 quadrant; BK=64; reg-staged prefetch.
__global__ __launch_bounds__(256) void gemm128(const unsigned short* __restrict__ A,
    const unsigned short* __restrict__ Bw, const float* __restrict__ bias,
    float* __restrict__ C, int M, int N, int K){
  __shared__ unsigned short As[128][72];
  __shared__ unsigned short Bs[128][72];
  int tid = threadIdx.x, w = tid >> 6, lane = tid & 63;
  int wr = w >> 1, wc = w & 1;
  int m0 = blockIdx.x*128, n0 = blockIdx.y*128;
  int l15 = lane & 15, lg = lane >> 4, kb = lg*8;
  int lr = tid >> 3, lc = (tid & 7)*8;    // staging: rows lr + j*32, col lc
  f32x4 acc[4][4] = {};
  us8 ra[4], rb[4];
  #pragma unroll
  for (int j = 0; j < 4; ++j){
    ra[j] = *(const us8*)(A  + (size_t)(m0 + lr + j*32)*K + lc);
    rb[j] = *(const us8*)(Bw + (size_t)(n0 + lr + j*32)*K + lc);
  }
  for (int kt = 0; kt < K; kt += 64){
    __syncthreads();                       // prev-iter reads done
    #pragma unroll
    for (int j = 0; j < 4; ++j){
      *(us8*)&As[lr + j*32][lc] = ra[j];
      *(us8*)&Bs[lr + j*32][lc] = rb[j];
    }
    if (kt + 64 < K){
      #pragma unroll
      for (int j = 0; j < 4; ++j){
        ra[j] = *(const us8*)(A  + (size_t)(m0 + lr + j*32)*K + kt + 64 + lc);
        rb[j] = *(const us8*)(Bw + (size_t)(n0 + lr + j*32)*K + kt + 64 + lc);
      }
    }
    __syncthreads();                       // LDS populated
    bf16x8 bf[4][2];
    #pragma unroll
    for (int ni = 0; ni < 4; ++ni){
      bf[ni][0] = *(const bf16x8*)&Bs[wc*64 + ni*16 + l15][kb];
      bf[ni][1] = *(const bf16x8*)&Bs[wc*64 + ni*16 + l15][32 + kb];
    }
    #pragma unroll
    for (int mi = 0; mi < 4; ++mi){
      bf16x8 af0 = *(const bf16x8*)&As[wr*64 + mi*16 + l15][kb];
      bf16x8 af1 = *(const bf16x8*)&As[wr*64 + mi*16 + l15][32 + kb];
      #pragma unroll
      for (int ni = 0; ni < 4; ++ni){
        acc[mi][ni] = __builtin_amdgcn_mfma_f32_16x16x32_bf16(af0, bf[ni][0], acc[mi][ni], 0,0,0);
        acc[mi][ni] = __builtin_amdgcn_mfma_f32_16x16x32_bf16(af1, bf[ni][1], acc[mi][ni], 0,0,0);
      }
    }
  }
  #pragma unroll
  for (int mi = 0; mi < 4; ++mi){
    int row = m0 + wr*64 + mi*16 + lg*4;
    #pragma unroll
    for (int ni = 0; ni < 4; ++ni){
      int col = n0 + wc*64 + ni*16 + l15;
      float bv_ = bias[col];
      #pragma unroll
      for (int r = 0; r < 4; ++r)
        C[(size_t)(row + r)*N + col] = acc[mi][ni][r] + bv_;
    }
  }
}

// ---- RoPE + rank contraction: build Q,K,V (B,H,S,D) bf16.
// Q folds 1/sqrt(64)/ln2 so attention can use exp2. ----
__global__ __launch_bounds__(256) void qkv_kernel(const float* __restrict__ proj,
    const float* __restrict__ cosT, const float* __restrict__ sinT,
    unsigned short* __restrict__ Q, unsigned short* __restrict__ K,
    unsigned short* __restrict__ V){
  int token = blockIdx.x; int b = token >> 11; int s = token & 2047;
  const float* row = proj + (size_t)token*NPROJP;
  __shared__ float aq[96], ak[32], av[32], bq[QR][HD], bk[KVR][HD], bv[KVR][HD];
  int t = threadIdx.x;
  for (int i = t; i < 800; i += 256){
    float vv = row[i];
    if (i < 96) aq[i] = vv;
    else if (i < 128) ak[i-96] = vv;
    else if (i < 160) av[i-128] = vv;
    else if (i < 544) (&bq[0][0])[i-160] = vv;
    else if (i < 672) (&bk[0][0])[i-544] = vv;
    else (&bv[0][0])[i-672] = vv;
  }
  __syncthreads();
  {
    if (t < 192){
      int r = t >> 5, i = t & 31;
      float c = cosT[s*32+i], sn = sinT[s*32+i];
      float x1 = bq[r][2*i], x2 = bq[r][2*i+1];
      bq[r][2*i]   = x1*c - x2*sn;
      bq[r][2*i+1] = x1*sn + x2*c;
    } else {
      int r = (t-192) >> 5, i = t & 31;
      float c = cosT[s*32+i], sn = sinT[s*32+i];
      float x1 = bk[r][2*i], x2 = bk[r][2*i+1];
      bk[r][2*i]   = x1*c - x2*sn;
      bk[r][2*i+1] = x1*sn + x2*c;
    }
  }
  __syncthreads();
  int h = t >> 4; int dbase = (t & 15)*4;
  float qv[4] = {}, kv[4] = {}, vv[4] = {};
  #pragma unroll
  for (int r = 0; r < QR; ++r){
    float a = aq[h*QR + r];
    #pragma unroll
    for (int j = 0; j < 4; ++j) qv[j] += a * bq[r][dbase+j];
  }
  #pragma unroll
  for (int r = 0; r < KVR; ++r){
    float a1 = ak[h*KVR + r], a2 = av[h*KVR + r];
    #pragma unroll
    for (int j = 0; j < 4; ++j){ kv[j] += a1 * bk[r][dbase+j]; vv[j] += a2 * bv[r][dbase+j]; }
  }
  size_t base = ((size_t)(b*NH + h)*SEQ + s)*HD + dbase;
  const float QS = 0.18033688f;  // 0.125 / ln(2)
  ushort4 qo; qo.x=f2bf(qv[0]*QS); qo.y=f2bf(qv[1]*QS); qo.z=f2bf(qv[2]*QS); qo.w=f2bf(qv[3]*QS);
  ushort4 ko; ko.x=f2bf(kv[0]); ko.y=f2bf(kv[1]); ko.z=f2bf(kv[2]); ko.w=f2bf(kv[3]);
  ushort4 vo; vo.x=f2bf(vv[0]); vo.y=f2bf(vv[1]); vo.z=f2bf(vv[2]); vo.w=f2bf(vv[3]);
  *(ushort4*)(Q+base) = qo;
  *(ushort4*)(K+base) = ko;
  *(ushort4*)(V+base) = vo;
}

// ---- one-shot V transpose: V[bh][s][d] -> VT[bh][d][s] ----
__global__ __launch_bounds__(256) void transpose_v(const unsigned short* __restrict__ V,
    unsigned short* __restrict__ VT){
  __shared__ unsigned short tile[64][72];
  int bh = blockIdx.y; int s0 = blockIdx.x*64;
  int tid = threadIdx.x;
  int r = tid >> 3, c = (tid & 7)*8;
  const unsigned short* src = V + ((size_t)bh*SEQ + s0)*HD;
  *(us8*)&tile[r][c]    = *(const us8*)(src + (size_t)r*HD + c);
  *(us8*)&tile[r+32][c] = *(const us8*)(src + (size_t)(r+32)*HD + c);
  __syncthreads();
  unsigned short* dst = VT + (size_t)bh*HD*SEQ + s0;
  us8 o0, o1;
  #pragma unroll
  for (int j = 0; j < 8; ++j){ o0[j] = tile[c+j][r]; o1[j] = tile[c+j][r+32]; }
  *(us8*)(dst + (size_t)r*SEQ + c)      = o0;
  *(us8*)(dst + (size_t)(r+32)*SEQ + c) = o1;
}

// ---- causal flash attention, swapped-operand softmax.
// QK^T computed as mfma(K,Q) -> D[k][q]: q = lane&15 (lane-local row stats).
// PV computed as mfma(V^T, P^T) -> D[d][q]: rescale + divide stay lane-local.
// 64 q-rows/block (4 waves x 16), KVBLK=64, dbuf LDS, 1 barrier/tile.
__global__ __launch_bounds__(256) void attn_kernel(const unsigned short* __restrict__ Q,
   const unsigned short* __restrict__ K, const unsigned short* __restrict__ VT,
   unsigned short* __restrict__ attnOut){
  __shared__ unsigned short Ks[2][64][72];
  __shared__ unsigned short Vs[2][64][72];   // transposed: [d][k]
  __shared__ unsigned short Pw[4][16][72];   // per-wave P: [q][k]
  int tid = threadIdx.x, w = tid >> 6, lane = tid & 63;
  int id = blockIdx.x;
  int xcd = id & 7, slot = id >> 3;          // 4 bh per XCD -> K/V L2-resident
  int bh  = xcd*4 + (slot & 3);
  int qblk = 31 - (slot >> 2);               // heavy q-tiles first
  int b = bh >> 4, h = bh & 15;
  const unsigned short* Qp = Q  + (size_t)bh*SEQ*HD;
  const unsigned short* Kp = K  + (size_t)bh*SEQ*HD;
  const unsigned short* Vp = VT + (size_t)bh*HD*SEQ;
  int l15 = lane & 15, lg = lane >> 4;
  int kb = lg*8;
  int qrow = qblk*64 + w*16 + l15;
  bf16x8 aq0 = *(const bf16x8*)(Qp + (size_t)qrow*HD + kb);
  bf16x8 aq1 = *(const bf16x8*)(Qp + (size_t)qrow*HD + 32 + kb);
  float m = -1e30f, l = 0.f;
  f32x4 o[4] = {};
  int ntile = qblk + 1;
  int lr = tid >> 3, lc = (tid & 7)*8;       // staging: rows lr,lr+32 x col lc
  us8 cka = *(const us8*)(Kp + (size_t)lr*HD + lc);
  us8 ckb = *(const us8*)(Kp + (size_t)(lr+32)*HD + lc);
  us8 cva = *(const us8*)(Vp + (size_t)lr*SEQ + lc);
  us8 cvb = *(const us8*)(Vp + (size_t)(lr+32)*SEQ + lc);
  for (int t = 0; t < ntile; ++t){
    int buf = t & 1;
    *(us8*)&Ks[buf][lr][lc]    = cka;
    *(us8*)&Ks[buf][lr+32][lc] = ckb;
    *(us8*)&Vs[buf][lr][lc]    = cva;
    *(us8*)&Vs[buf][lr+32][lc] = cvb;
    if (t + 1 < ntile){                      // prefetch next tile
      int k1 = (t+1)*64;
      cka = *(const us8*)(Kp + (size_t)(k1+lr)*HD + lc);
      ckb = *(const us8*)(Kp + (size_t)(k1+lr+32)*HD + lc);
      cva = *(const us8*)(Vp + (size_t)lr*SEQ + k1 + lc);
      cvb = *(const us8*)(Vp + (size_t)(lr+32)*SEQ + k1 + lc);
    }
    __syncthreads();
    // QK^T swapped: sf[f] holds S[k = f*16 + lg*4 + r][q = l15]
    f32x4 sf[4];
    #pragma unroll
    for (int f = 0; f < 4; ++f){
      f32x4 z = {};
      bf16x8 kf0 = *(const bf16x8*)&Ks[buf][f*16 + l15][kb];
      bf16x8 kf1 = *(const bf16x8*)&Ks[buf][f*16 + l15][32 + kb];
      z = __builtin_amdgcn_mfma_f32_16x16x32_bf16(kf0, aq0, z, 0,0,0);
      sf[f] = __builtin_amdgcn_mfma_f32_16x16x32_bf16(kf1, aq1, z, 0,0,0);
    }
    if (t == qblk){                          // diagonal tile: mask k > q
      int qloc = w*16 + l15;
      #pragma unroll
      for (int f = 0; f < 4; ++f)
        #pragma unroll
        for (int r = 0; r < 4; ++r)
          sf[f][r] = (f*16 + lg*4 + r) <= qloc ? sf[f][r] : -1e30f;
    }
    // in-lane 16-wide max, then 2 shfls across lg groups
    float c0 = fmaxf(fmaxf(sf[0][0], sf[0][1]), fmaxf(sf[0][2], sf[0][3]));
    float c1 = fmaxf(fmaxf(sf[1][0], sf[1][1]), fmaxf(sf[1][2], sf[1][3]));
    float c2 = fmaxf(fmaxf(sf[2][0], sf[2][1]), fmaxf(sf[2][2], sf[2][3]));
    float c3 = fmaxf(fmaxf(sf[3][0], sf[3][1]), fmaxf(sf[3][2], sf[3][3]));
    float cmax = fmaxf(fmaxf(c0, c1), fmaxf(c2, c3));
    cmax = fmaxf(cmax, __shfl_xor(cmax, 16));
    cmax = fmaxf(cmax, __shfl_xor(cmax, 32));
    float mn = fmaxf(m, cmax);
    float alpha = exp2f(m - mn);
    m = mn;
    float p[4][4];
    float rs = 0.f;
    #pragma unroll
    for (int f = 0; f < 4; ++f){
      float s0 = exp2f(sf[f][0] - mn), s1 = exp2f(sf[f][1] - mn);
      float s2 = exp2f(sf[f][2] - mn), s3 = exp2f(sf[f][3] - mn);
      p[f][0]=s0; p[f][1]=s1; p[f][2]=s2; p[f][3]=s3;
      rs += (s0 + s1) + (s2 + s3);
    }
    rs += __shfl_xor(rs, 16);
    rs += __shfl_xor(rs, 32);
    l = l*alpha + rs;
    #pragma unroll
    for (int nd = 0; nd < 4; ++nd){
      o[nd][0] *= alpha; o[nd][1] *= alpha; o[nd][2] *= alpha; o[nd][3] *= alpha;
    }
    // pack P[q=l15][k] into LDS: 4x b64 writes
    #pragma unroll
    for (int f = 0; f < 4; ++f){
      uint2 u; u.x = pkbf(p[f][0], p[f][1]); u.y = pkbf(p[f][2], p[f][3]);
      *(uint2*)&Pw[w][l15][f*16 + lg*4] = u;
    }
    bf16x8 pf0 = *(const bf16x8*)&Pw[w][l15][kb];
    bf16x8 pf1 = *(const bf16x8*)&Pw[w][l15][32 + kb];
    #pragma unroll
    for (int nd = 0; nd < 4; ++nd){
      bf16x8 vf0 = *(const bf16x8*)&Vs[buf][nd*16 + l15][kb];
      bf16x8 vf1 = *(const bf16x8*)&Vs[buf][nd*16 + l15][32 + kb];
      o[nd] = __builtin_amdgcn_mfma_f32_16x16x32_bf16(vf0, pf0, o[nd], 0,0,0);
      o[nd] = __builtin_amdgcn_mfma_f32_16x16x32_bf16(vf1, pf1, o[nd], 0,0,0);
    }
  }
  float inv = 1.0f / l;
  #pragma unroll
  for (int nd = 0; nd < 4; ++nd){
    // O[d = nd*16 + lg*4 + r][q = l15]; write 4 bf16 (d-contiguous) per nd
    uint2 u;
    u.x = pkbf(o[nd][0]*inv, o[nd][1]*inv);
    u.y = pkbf(o[nd][2]*inv, o[nd][3]*inv);
    *(uint2*)(attnOut + ((size_t)b*SEQ + qrow)*DM + h*HD + nd*16 + lg*4) = u;
  }
}

extern "C" void kernel_launch(void* const* d_in, const int* in_sizes, int n_in,
                              void* d_out, int out_size, void* d_ws, size_t ws_size,
                              hipStream_t stream){
  const float* x   = (const float*)d_in[0];
  const float* Waq = (const float*)d_in[1];
  const float* baq = (const float*)d_in[2];
  const float* Wbq = (const float*)d_in[3];
  const float* bbq = (const float*)d_in[4];
  const float* Wak = (const float*)d_in[5];
  const float* bak = (const float*)d_in[6];
  const float* Wbk = (const float*)d_in[7];
  const float* bbk = (const float*)d_in[8];
  const float* Wav = (const float*)d_in[9];
  const float* bav = (const float*)d_in[10];
  const float* Wbv = (const float*)d_in[11];
  const float* bbv = (const float*)d_in[12];
  const float* Wo  = (const float*)d_in[13];
  const float* bo  = (const float*)d_in[14];
  const float* cosT= (const float*)d_in[15];
  const float* sinT= (const float*)d_in[16];
  float* out = (float*)d_out;

  char* ws = (char*)d_ws;
  // xb reused as VTb after gemm1 consumes it
  unsigned short* xb    = (unsigned short*)(ws + 0);          // 8.4 MB
  unsigned short* VTb   = (unsigned short*)(ws + 0);          // reuse of xb
  unsigned short* Wob   = (unsigned short*)(ws + 8388608);    // 2.1 MB
  unsigned short* Wcat  = (unsigned short*)(ws + 10485760);   // 896x1024x2 = 1.84 MB
  float*          bcat  = (float*)(ws + 12320768);            // 3.6 KB
  float*          proj  = (float*)(ws + 12324352);            // 4096x896x4 = 14.7 MB
  unsigned short* Qb    = (unsigned short*)(ws + 27004416);   // 8.4 MB
  unsigned short* Kb    = (unsigned short*)(ws + 35393024);   // 8.4 MB
  unsigned short* Vb    = (unsigned short*)(ws + 43781632);   // 8.4 MB
  unsigned short* attnB = (unsigned short*)(ws + 52170240);   // 8.4 MB

  cast_kernel<<<4096, 256, 0, stream>>>(x, xb, 1048576);
  cast_kernel<<<1024, 256, 0, stream>>>(Wo, Wob, 262144);
  build_wcat<<<NPROJP, 256, 0, stream>>>(Waq, Wak, Wav, Wbq, Wbk, Wbv,
                                         baq, bak, bav, bbq, bbk, bbv, Wcat, bcat);
  gemm128<<<dim3(32,7), 256, 0, stream>>>(xb, Wcat, bcat, proj, NTOK, NPROJP, DM);
  qkv_kernel<<<4096, 256, 0, stream>>>(proj, cosT, sinT, Qb, Kb, Vb);
  transpose_v<<<dim3(32,32), 256, 0, stream>>>(Vb, VTb);
  attn_kernel<<<1024, 256, 0, stream>>>(Qb, Kb, VTb, attnB);
  gemm128<<<dim3(32,8), 256, 0, stream>>>(attnB, Wob, bo, out, NTOK, DM, DM);
}

// Round 5
// 107.017 us; speedup vs baseline: 2.7527x; 1.0569x over previous
//
#include <hip/hip_runtime.h>
#include <stdint.h>

#define BATCH 2
#define SEQ 2048
#define DM 1024
#define NH 16
#define HD 64
#define QR 6
#define KVR 2
#define NTOK (BATCH*SEQ)
#define NPROJ 832    // live projection outputs
#define NPROJP 896   // padded to 7*128 for 128-tile GEMM

typedef __bf16 bf16x8 __attribute__((ext_vector_type(8)));
typedef float f32x4 __attribute__((ext_vector_type(4)));
typedef unsigned short us8 __attribute__((ext_vector_type(8)));

__device__ inline unsigned short f2bf(float f){
  union { float f; unsigned int u; } v; v.f = f;
  unsigned int r = (v.u + 0x7fffu + ((v.u >> 16) & 1u)) >> 16;
  return (unsigned short)r;
}
__device__ __forceinline__ unsigned short bfr(float f){
  __bf16 h = (__bf16)f;
  return *(unsigned short*)&h;
}
// async global->LDS, 16B per lane; dest = wave-uniform base + lane*16
__device__ __forceinline__ void gl16(const void* g, void* l){
  __builtin_amdgcn_global_load_lds(
      (const __attribute__((address_space(1))) void*)g,
      (__attribute__((address_space(3))) void*)l, 16, 0, 0);
}

// ---- cast f32 -> bf16, 4 elems/thread ----
__global__ void cast_kernel(const float* __restrict__ in, unsigned short* __restrict__ out, int n4){
  int i = blockIdx.x*blockDim.x + threadIdx.x;
  if (i >= n4) return;
  float4 v = ((const float4*)in)[i];
  ushort4 o; o.x = f2bf(v.x); o.y = f2bf(v.y); o.z = f2bf(v.z); o.w = f2bf(v.w);
  ((ushort4*)out)[i] = o;
}

// ---- build concatenated weight (896x1024 bf16, zero-padded) + bias ----
__global__ void build_wcat(const float* __restrict__ Waq, const float* __restrict__ Wak,
                           const float* __restrict__ Wav, const float* __restrict__ Wbq,
                           const float* __restrict__ Wbk, const float* __restrict__ Wbv,
                           const float* __restrict__ baq, const float* __restrict__ bak,
                           const float* __restrict__ bav, const float* __restrict__ bbq,
                           const float* __restrict__ bbk, const float* __restrict__ bbv,
                           unsigned short* __restrict__ Wcat, float* __restrict__ bcat){
  int n = blockIdx.x; int t = threadIdx.x;
  const float* src = nullptr; float bv_ = 0.f;
  if (n < 96)       { src = Waq + (size_t)n*DM;        bv_ = baq[n]; }
  else if (n < 128) { src = Wak + (size_t)(n-96)*DM;   bv_ = bak[n-96]; }
  else if (n < 160) { src = Wav + (size_t)(n-128)*DM;  bv_ = bav[n-128]; }
  else if (n < 544) { src = Wbq + (size_t)(n-160)*DM;  bv_ = bbq[n-160]; }
  else if (n < 672) { src = Wbk + (size_t)(n-544)*DM;  bv_ = bbk[n-544]; }
  else if (n < 800) { src = Wbv + (size_t)(n-672)*DM;  bv_ = bbv[n-672]; }
  unsigned short* dst = Wcat + (size_t)n*DM;
  if (src){
    float4 v = ((const float4*)src)[t];
    ushort4 o; o.x = f2bf(v.x); o.y = f2bf(v.y); o.z = f2bf(v.z); o.w = f2bf(v.w);
    ((ushort4*)dst)[t] = o;
  } else {
    ushort4 z = {0,0,0,0};
    ((ushort4*)dst)[t] = z;
  }
  if (t == 0) bcat[n] = bv_;
}

// ---- 128x128-tile NT bf16 GEMM via global_load_lds, XOR-swizzled LDS.
// C[M,N] = A[M,K]*Bw[N,K]^T + bias. 4 waves, 64x64 quadrant each, BK=64.
__global__ __launch_bounds__(256, 2) void gemm128(const unsigned short* __restrict__ A,
    const unsigned short* __restrict__ Bw, const float* __restrict__ bias,
    float* __restrict__ C, int M, int N, int K){
  __shared__ unsigned short As[2][128][64];
  __shared__ unsigned short Bs[2][128][64];
  int tid = threadIdx.x, w = tid >> 6, lane = tid & 63;
  int wr = w >> 1, wc = w & 1;
  int m0 = blockIdx.x*128, n0 = blockIdx.y*128;
  int l15 = lane & 15, lg = lane >> 4;
  int u = lg ^ (l15 & 7);
  int c0 = u*8, c1 = (u^4)*8;
  // staging: wave w stages rows [w*32, w*32+32); lane: row w*32+j*8+(lane>>3),
  // source col XOR-swizzled by row&7 so linear LDS + swizzled read = conflict-free
  int srow = (lane >> 3);                    // = row&7
  int scol = ((lane & 7) ^ srow) * 8;
  const unsigned short* Ag = A  + (size_t)(m0 + w*32 + srow)*K + scol;
  const unsigned short* Bg = Bw + (size_t)(n0 + w*32 + srow)*K + scol;
  size_t K8 = (size_t)8*K;
  f32x4 acc[4][4] = {};
  // prologue: stage k-step 0 into buf 0
  #pragma unroll
  for (int j = 0; j < 4; ++j){
    gl16(Ag + (size_t)j*K8, &As[0][w*32 + j*8][0]);
    gl16(Bg + (size_t)j*K8, &Bs[0][w*32 + j*8][0]);
  }
  int nsteps = K >> 6;
  for (int s = 0; s < nsteps; ++s){
    int buf = s & 1;
    __syncthreads();                         // drains glds of this buf
    if (s + 1 < nsteps){
      int nb = buf ^ 1;
      const unsigned short* An = Ag + (s+1)*64;
      const unsigned short* Bn = Bg + (s+1)*64;
      #pragma unroll
      for (int j = 0; j < 4; ++j){
        gl16(An + (size_t)j*K8, &As[nb][w*32 + j*8][0]);
        gl16(Bn + (size_t)j*K8, &Bs[nb][w*32 + j*8][0]);
      }
    }
    bf16x8 bf[4][2];
    #pragma unroll
    for (int ni = 0; ni < 4; ++ni){
      bf[ni][0] = *(const bf16x8*)&Bs[buf][wc*64 + ni*16 + l15][c0];
      bf[ni][1] = *(const bf16x8*)&Bs[buf][wc*64 + ni*16 + l15][c1];
    }
    #pragma unroll
    for (int mi = 0; mi < 4; ++mi){
      bf16x8 af0 = *(const bf16x8*)&As[buf][wr*64 + mi*16 + l15][c0];
      bf16x8 af1 = *(const bf16x8*)&As[buf][wr*64 + mi*16 + l15][c1];
      #pragma unroll
      for (int ni = 0; ni < 4; ++ni){
        acc[mi][ni] = __builtin_amdgcn_mfma_f32_16x16x32_bf16(af0, bf[ni][0], acc[mi][ni], 0,0,0);
        acc[mi][ni] = __builtin_amdgcn_mfma_f32_16x16x32_bf16(af1, bf[ni][1], acc[mi][ni], 0,0,0);
      }
    }
  }
  #pragma unroll
  for (int mi = 0; mi < 4; ++mi){
    int row = m0 + wr*64 + mi*16 + lg*4;
    #pragma unroll
    for (int ni = 0; ni < 4; ++ni){
      int col = n0 + wc*64 + ni*16 + l15;
      float bv_ = bias[col];
      #pragma unroll
      for (int r = 0; r < 4; ++r)
        C[(size_t)(row + r)*N + col] = acc[mi][ni][r] + bv_;
    }
  }
}

// ---- RoPE + rank contraction: build Q,K,V (B,H,S,D) bf16.
// Q folds 1/sqrt(64)/ln2 so attention can use exp2. ----
__global__ __launch_bounds__(256) void qkv_kernel(const float* __restrict__ proj,
    const float* __restrict__ cosT, const float* __restrict__ sinT,
    unsigned short* __restrict__ Q, unsigned short* __restrict__ K,
    unsigned short* __restrict__ V){
  int token = blockIdx.x; int b = token >> 11; int s = token & 2047;
  const float* row = proj + (size_t)token*NPROJP;
  __shared__ float aq[96], ak[32], av[32], bq[QR][HD], bk[KVR][HD], bv[KVR][HD];
  int t = threadIdx.x;
  for (int i = t; i < 800; i += 256){
    float vv = row[i];
    if (i < 96) aq[i] = vv;
    else if (i < 128) ak[i-96] = vv;
    else if (i < 160) av[i-128] = vv;
    else if (i < 544) (&bq[0][0])[i-160] = vv;
    else if (i < 672) (&bk[0][0])[i-544] = vv;
    else (&bv[0][0])[i-672] = vv;
  }
  __syncthreads();
  {
    if (t < 192){
      int r = t >> 5, i = t & 31;
      float c = cosT[s*32+i], sn = sinT[s*32+i];
      float x1 = bq[r][2*i], x2 = bq[r][2*i+1];
      bq[r][2*i]   = x1*c - x2*sn;
      bq[r][2*i+1] = x1*sn + x2*c;
    } else {
      int r = (t-192) >> 5, i = t & 31;
      float c = cosT[s*32+i], sn = sinT[s*32+i];
      float x1 = bk[r][2*i], x2 = bk[r][2*i+1];
      bk[r][2*i]   = x1*c - x2*sn;
      bk[r][2*i+1] = x1*sn + x2*c;
    }
  }
  __syncthreads();
  int h = t >> 4; int dbase = (t & 15)*4;
  float qv[4] = {}, kv[4] = {}, vv[4] = {};
  #pragma unroll
  for (int r = 0; r < QR; ++r){
    float a = aq[h*QR + r];
    #pragma unroll
    for (int j = 0; j < 4; ++j) qv[j] += a * bq[r][dbase+j];
  }
  #pragma unroll
  for (int r = 0; r < KVR; ++r){
    float a1 = ak[h*KVR + r], a2 = av[h*KVR + r];
    #pragma unroll
    for (int j = 0; j < 4; ++j){ kv[j] += a1 * bk[r][dbase+j]; vv[j] += a2 * bv[r][dbase+j]; }
  }
  size_t base = ((size_t)(b*NH + h)*SEQ + s)*HD + dbase;
  const float QS = 0.18033688f;  // 0.125 / ln(2)
  ushort4 qo; qo.x=f2bf(qv[0]*QS); qo.y=f2bf(qv[1]*QS); qo.z=f2bf(qv[2]*QS); qo.w=f2bf(qv[3]*QS);
  ushort4 ko; ko.x=f2bf(kv[0]); ko.y=f2bf(kv[1]); ko.z=f2bf(kv[2]); ko.w=f2bf(kv[3]);
  ushort4 vo; vo.x=f2bf(vv[0]); vo.y=f2bf(vv[1]); vo.z=f2bf(vv[2]); vo.w=f2bf(vv[3]);
  *(ushort4*)(Q+base) = qo;
  *(ushort4*)(K+base) = ko;
  *(ushort4*)(V+base) = vo;
}

// ---- one-shot V transpose: V[bh][s][d] -> VT[bh][d][s] ----
__global__ __launch_bounds__(256) void transpose_v(const unsigned short* __restrict__ V,
    unsigned short* __restrict__ VT){
  __shared__ unsigned short tile[64][66];
  int bh = blockIdx.y; int s0 = blockIdx.x*64;
  int tid = threadIdx.x;
  int r = tid >> 3, c = (tid & 7)*8;
  const unsigned short* src = V + ((size_t)bh*SEQ + s0)*HD;
  *(us8*)&tile[r][c]    = *(const us8*)(src + (size_t)r*HD + c);
  *(us8*)&tile[r+32][c] = *(const us8*)(src + (size_t)(r+32)*HD + c);
  __syncthreads();
  unsigned short* dst = VT + (size_t)bh*HD*SEQ + s0;
  us8 o0, o1;
  #pragma unroll
  for (int j = 0; j < 8; ++j){ o0[j] = tile[c+j][r]; o1[j] = tile[c+j][r+32]; }
  *(us8*)(dst + (size_t)r*SEQ + c)      = o0;
  *(us8*)(dst + (size_t)(r+32)*SEQ + c) = o1;
}

// ---- causal flash attention, no-max softmax (scores bounded), paired q-tiles.
// grid 512: each block does q-tiles {31-pi, pi} (33 KV-tiles total -> perfect
// balance, exactly 2 blocks/CU... 4 fit by LDS=40KB). glds K/V staging,
// XOR-swizzled LDS, swapped-operand MFMA (q lane-local), zero in-loop shfls.
__global__ __launch_bounds__(256, 4) void attn_kernel(const unsigned short* __restrict__ Q,
   const unsigned short* __restrict__ K, const unsigned short* __restrict__ VT,
   unsigned short* __restrict__ attnOut){
  __shared__ unsigned short Ks[2][64][64];   // 16 KB
  __shared__ unsigned short Vs[2][64][64];   // 16 KB (transposed: [d][k])
  __shared__ unsigned short Pw[4][16][64];   // 8 KB, per-wave P: [q][k]
  int tid = threadIdx.x, w = tid >> 6, lane = tid & 63;
  int id = blockIdx.x;
  int xcd = id & 7, slot = id >> 3;          // 4 bh per XCD -> K/V L2-resident
  int bh  = xcd*4 + (slot & 3);
  int pi  = slot >> 2;                       // 0..15
  int b = bh >> 4, h = bh & 15;
  const unsigned short* Qp = Q  + (size_t)bh*SEQ*HD;
  const unsigned short* Kp = K  + (size_t)bh*SEQ*HD;
  const unsigned short* Vp = VT + (size_t)bh*HD*SEQ;
  int l15 = lane & 15, lg = lane >> 4;
  int u = lg ^ (l15 & 7);
  int c0 = u*8, c1 = (u^4)*8;                // swizzled frag columns
  int w16 = w*16;
  int srow = lane >> 3;                      // staging row-within-8 (= row&7)
  int scol = ((lane & 7) ^ srow) * 8;        // inverse-swizzled source col
  const unsigned short* Kg = Kp + (size_t)(w16 + srow)*HD + scol;
  const unsigned short* Vg = Vp + (size_t)(w16 + srow)*SEQ + scol;
  int pcolbase = ((l15 & 7) * 8);
  for (int seg = 0; seg < 2; ++seg){
    int qblk = seg ? pi : 31 - pi;           // heavy q-tile first
    int ntile = qblk + 1;
    int qrow = qblk*64 + w16 + l15;
    bf16x8 aq0 = *(const bf16x8*)(Qp + (size_t)qrow*HD + lg*8);
    bf16x8 aq1 = *(const bf16x8*)(Qp + (size_t)qrow*HD + 32 + lg*8);
    f32x4 o[4] = {};
    float lsum = 0.f;
    __syncthreads();                         // prev seg done reading LDS
    gl16(Kg,         &Ks[0][w16][0]);
    gl16(Kg + 512,   &Ks[0][w16+8][0]);      // +8 rows * 64
    gl16(Vg,         &Vs[0][w16][0]);
    gl16(Vg + 16384, &Vs[0][w16+8][0]);      // +8 rows * SEQ
    for (int t = 0; t < ntile; ++t){
      int buf = t & 1;
      __syncthreads();                       // drains glds for this buf
      if (t + 1 < ntile){
        int nb = buf ^ 1;
        const unsigned short* kg = Kg + (size_t)(t+1)*64*HD;
        const unsigned short* vg = Vg + (t+1)*64;
        gl16(kg,         &Ks[nb][w16][0]);
        gl16(kg + 512,   &Ks[nb][w16+8][0]);
        gl16(vg,         &Vs[nb][w16][0]);
        gl16(vg + 16384, &Vs[nb][w16+8][0]);
      }
      // QK^T swapped: sf[f] = S[k = f*16 + lg*4 + r][q = l15]
      f32x4 sf[4];
      #pragma unroll
      for (int f = 0; f < 4; ++f){
        f32x4 z = {};
        bf16x8 kf0 = *(const bf16x8*)&Ks[buf][f*16 + l15][c0];
        bf16x8 kf1 = *(const bf16x8*)&Ks[buf][f*16 + l15][c1];
        z = __builtin_amdgcn_mfma_f32_16x16x32_bf16(kf0, aq0, z, 0,0,0);
        sf[f] = __builtin_amdgcn_mfma_f32_16x16x32_bf16(kf1, aq1, z, 0,0,0);
      }
      if (t == qblk){                        // diagonal tile: mask k > q
        int qloc = w16 + l15;
        #pragma unroll
        for (int f = 0; f < 4; ++f)
          #pragma unroll
          for (int r = 0; r < 4; ++r)
            sf[f][r] = (f*16 + lg*4 + r) <= qloc ? sf[f][r] : -1e30f;
      }
      // no-max softmax: p = exp2(s) directly (scores bounded ~|5|)
      float rs = 0.f;
      ushort4 pu[4];
      #pragma unroll
      for (int f = 0; f < 4; ++f){
        float e0 = exp2f(sf[f][0]), e1 = exp2f(sf[f][1]);
        float e2 = exp2f(sf[f][2]), e3 = exp2f(sf[f][3]);
        rs += (e0 + e1) + (e2 + e3);
        pu[f].x = bfr(e0); pu[f].y = bfr(e1); pu[f].z = bfr(e2); pu[f].w = bfr(e3);
      }
      lsum += rs;
      #pragma unroll
      for (int f = 0; f < 4; ++f)
        *(ushort4*)&Pw[w][l15][(f*16 + lg*4) ^ pcolbase] = pu[f];
      bf16x8 pf0 = *(const bf16x8*)&Pw[w][l15][c0];
      bf16x8 pf1 = *(const bf16x8*)&Pw[w][l15][c1];
      #pragma unroll
      for (int nd = 0; nd < 4; ++nd){
        bf16x8 vf0 = *(const bf16x8*)&Vs[buf][nd*16 + l15][c0];
        bf16x8 vf1 = *(const bf16x8*)&Vs[buf][nd*16 + l15][c1];
        o[nd] = __builtin_amdgcn_mfma_f32_16x16x32_bf16(vf0, pf0, o[nd], 0,0,0);
        o[nd] = __builtin_amdgcn_mfma_f32_16x16x32_bf16(vf1, pf1, o[nd], 0,0,0);
      }
    }
    // row-sum across the 4 lg-lanes (once per seg), then write O[d][q]
    lsum += __shfl_xor(lsum, 16);
    lsum += __shfl_xor(lsum, 32);
    float inv = 1.0f / lsum;
    #pragma unroll
    for (int nd = 0; nd < 4; ++nd){
      ushort4 ov;
      ov.x = bfr(o[nd][0]*inv); ov.y = bfr(o[nd][1]*inv);
      ov.z = bfr(o[nd][2]*inv); ov.w = bfr(o[nd][3]*inv);
      *(ushort4*)(attnOut + ((size_t)b*SEQ + qrow)*DM + h*HD + nd*16 + lg*4) = ov;
    }
  }
}

extern "C" void kernel_launch(void* const* d_in, const int* in_sizes, int n_in,
                              void* d_out, int out_size, void* d_ws, size_t ws_size,
                              hipStream_t stream){
  const float* x   = (const float*)d_in[0];
  const float* Waq = (const float*)d_in[1];
  const float* baq = (const float*)d_in[2];
  const float* Wbq = (const float*)d_in[3];
  const float* bbq = (const float*)d_in[4];
  const float* Wak = (const float*)d_in[5];
  const float* bak = (const float*)d_in[6];
  const float* Wbk = (const float*)d_in[7];
  const float* bbk = (const float*)d_in[8];
  const float* Wav = (const float*)d_in[9];
  const float* bav = (const float*)d_in[10];
  const float* Wbv = (const float*)d_in[11];
  const float* bbv = (const float*)d_in[12];
  const float* Wo  = (const float*)d_in[13];
  const float* bo  = (const float*)d_in[14];
  const float* cosT= (const float*)d_in[15];
  const float* sinT= (const float*)d_in[16];
  float* out = (float*)d_out;

  char* ws = (char*)d_ws;
  // xb reused as VTb after gemm1 consumes it
  unsigned short* xb    = (unsigned short*)(ws + 0);          // 8.4 MB
  unsigned short* VTb   = (unsigned short*)(ws + 0);          // reuse of xb
  unsigned short* Wob   = (unsigned short*)(ws + 8388608);    // 2.1 MB
  unsigned short* Wcat  = (unsigned short*)(ws + 10485760);   // 896x1024x2 = 1.84 MB
  float*          bcat  = (float*)(ws + 12320768);            // 3.6 KB
  float*          proj  = (float*)(ws + 12324352);            // 4096x896x4 = 14.7 MB
  unsigned short* Qb    = (unsigned short*)(ws + 27004416);   // 8.4 MB
  unsigned short* Kb    = (unsigned short*)(ws + 35393024);   // 8.4 MB
  unsigned short* Vb    = (unsigned short*)(ws + 43781632);   // 8.4 MB
  unsigned short* attnB = (unsigned short*)(ws + 52170240);   // 8.4 MB

  cast_kernel<<<4096, 256, 0, stream>>>(x, xb, 1048576);
  cast_kernel<<<1024, 256, 0, stream>>>(Wo, Wob, 262144);
  build_wcat<<<NPROJP, 256, 0, stream>>>(Waq, Wak, Wav, Wbq, Wbk, Wbv,
                                         baq, bak, bav, bbq, bbk, bbv, Wcat, bcat);
  gemm128<<<dim3(32,7), 256, 0, stream>>>(xb, Wcat, bcat, proj, NTOK, NPROJP, DM);
  qkv_kernel<<<4096, 256, 0, stream>>>(proj, cosT, sinT, Qb, Kb, Vb);
  transpose_v<<<dim3(32,32), 256, 0, stream>>>(Vb, VTb);
  attn_kernel<<<512, 256, 0, stream>>>(Qb, Kb, VTb, attnB);
  gemm128<<<dim3(32,8), 256, 0, stream>>>(attnB, Wob, bo, out, NTOK, DM, DM);
}

// Round 6
// 106.377 us; speedup vs baseline: 2.7692x; 1.0060x over previous
//
#include <hip/hip_runtime.h>
#include <stdint.h>

#define BATCH 2
#define SEQ 2048
#define DM 1024
#define NH 16
#define HD 64
#define QR 6
#define KVR 2
#define NTOK (BATCH*SEQ)
#define NPROJ 832    // live projection outputs
#define NPROJP 896   // padded to 7*128 for 128-tile GEMM

typedef __bf16 bf16x8 __attribute__((ext_vector_type(8)));
typedef float f32x4 __attribute__((ext_vector_type(4)));
typedef unsigned short us8 __attribute__((ext_vector_type(8)));

#define SBAR __builtin_amdgcn_sched_barrier(0)

__device__ inline unsigned short f2bf(float f){
  union { float f; unsigned int u; } v; v.f = f;
  unsigned int r = (v.u + 0x7fffu + ((v.u >> 16) & 1u)) >> 16;
  return (unsigned short)r;
}
__device__ __forceinline__ unsigned short bfr(float f){
  __bf16 h = (__bf16)f;
  return *(unsigned short*)&h;
}
__device__ __forceinline__ float bf2f(unsigned short u){
  union { unsigned int i; float f; } v; v.i = ((unsigned int)u) << 16; return v.f;
}
// async global->LDS, 16B per lane; dest = wave-uniform base + lane*16
__device__ __forceinline__ void gl16(const void* g, void* l){
  __builtin_amdgcn_global_load_lds(
      (const __attribute__((address_space(1))) void*)g,
      (__attribute__((address_space(3))) void*)l, 16, 0, 0);
}

// ---- cast f32 -> bf16, 4 elems/thread ----
__global__ void cast_kernel(const float* __restrict__ in, unsigned short* __restrict__ out, int n4){
  int i = blockIdx.x*blockDim.x + threadIdx.x;
  if (i >= n4) return;
  float4 v = ((const float4*)in)[i];
  ushort4 o; o.x = f2bf(v.x); o.y = f2bf(v.y); o.z = f2bf(v.z); o.w = f2bf(v.w);
  ((ushort4*)out)[i] = o;
}

// ---- build concatenated weight (896x1024 bf16, zero-padded) + bias ----
__global__ void build_wcat(const float* __restrict__ Waq, const float* __restrict__ Wak,
                           const float* __restrict__ Wav, const float* __restrict__ Wbq,
                           const float* __restrict__ Wbk, const float* __restrict__ Wbv,
                           const float* __restrict__ baq, const float* __restrict__ bak,
                           const float* __restrict__ bav, const float* __restrict__ bbq,
                           const float* __restrict__ bbk, const float* __restrict__ bbv,
                           unsigned short* __restrict__ Wcat, float* __restrict__ bcat){
  int n = blockIdx.x; int t = threadIdx.x;
  const float* src = nullptr; float bv_ = 0.f;
  if (n < 96)       { src = Waq + (size_t)n*DM;        bv_ = baq[n]; }
  else if (n < 128) { src = Wak + (size_t)(n-96)*DM;   bv_ = bak[n-96]; }
  else if (n < 160) { src = Wav + (size_t)(n-128)*DM;  bv_ = bav[n-128]; }
  else if (n < 544) { src = Wbq + (size_t)(n-160)*DM;  bv_ = bbq[n-160]; }
  else if (n < 672) { src = Wbk + (size_t)(n-544)*DM;  bv_ = bbk[n-544]; }
  else if (n < 800) { src = Wbv + (size_t)(n-672)*DM;  bv_ = bbv[n-672]; }
  unsigned short* dst = Wcat + (size_t)n*DM;
  if (src){
    float4 v = ((const float4*)src)[t];
    ushort4 o; o.x = f2bf(v.x); o.y = f2bf(v.y); o.z = f2bf(v.z); o.w = f2bf(v.w);
    ((ushort4*)dst)[t] = o;
  } else {
    ushort4 z = {0,0,0,0};
    ((ushort4*)dst)[t] = z;
  }
  if (t == 0) bcat[n] = bv_;
}

// ---- 128x128-tile NT bf16 GEMM, 3-buffer 2-deep glds pipeline, counted vmcnt.
// C[M,N] = A[M,K]*Bw[N,K]^T + bias. 4 waves, 64x64 quadrant each, BK=64.
template<int OUT_BF16>
__global__ __launch_bounds__(256, 1) void gemm128(const unsigned short* __restrict__ A,
    const unsigned short* __restrict__ Bw, const float* __restrict__ bias,
    void* __restrict__ Cout, int M, int N, int K){
  __shared__ unsigned short As[3][128][64];
  __shared__ unsigned short Bs[3][128][64];
  int tid = threadIdx.x, w = tid >> 6, lane = tid & 63;
  int wr = w >> 1, wc = w & 1;
  int m0 = blockIdx.x*128, n0 = blockIdx.y*128;
  int l15 = lane & 15, lg = lane >> 4;
  int u = lg ^ (l15 & 7);
  int c0 = u*8, c1 = (u^4)*8;
  int srow = (lane >> 3);                    // = row&7
  int scol = ((lane & 7) ^ srow) * 8;        // inverse-swizzled source col
  const unsigned short* Ag = A  + (size_t)(m0 + w*32 + srow)*K + scol;
  const unsigned short* Bg = Bw + (size_t)(n0 + w*32 + srow)*K + scol;
  size_t K8 = (size_t)8*K;
  f32x4 acc[4][4] = {};
  int nsteps = K >> 6;
  auto STAGE = [&](int ss){
    int sb = ss % 3;
    const unsigned short* An = Ag + ss*64;
    const unsigned short* Bn = Bg + ss*64;
    #pragma unroll
    for (int j = 0; j < 4; ++j){
      gl16(An + (size_t)j*K8, &As[sb][w*32 + j*8][0]);
      gl16(Bn + (size_t)j*K8, &Bs[sb][w*32 + j*8][0]);
    }
  };
  STAGE(0); STAGE(1);
  for (int s = 0; s < nsteps; ++s){
    int buf = s % 3;
    SBAR; __builtin_amdgcn_s_barrier(); SBAR;      // B1: readers of stage-target done
    if (s + 2 < nsteps) STAGE(s + 2);
    if (s + 2 < nsteps)      asm volatile("s_waitcnt vmcnt(16)" ::: "memory");
    else if (s + 1 < nsteps) asm volatile("s_waitcnt vmcnt(8)"  ::: "memory");
    else                     asm volatile("s_waitcnt vmcnt(0)"  ::: "memory");
    SBAR;
    __builtin_amdgcn_s_barrier(); SBAR;            // B2: buf-s data landed everywhere
    bf16x8 bf[4][2];
    #pragma unroll
    for (int ni = 0; ni < 4; ++ni){
      bf[ni][0] = *(const bf16x8*)&Bs[buf][wc*64 + ni*16 + l15][c0];
      bf[ni][1] = *(const bf16x8*)&Bs[buf][wc*64 + ni*16 + l15][c1];
    }
    #pragma unroll
    for (int mi = 0; mi < 4; ++mi){
      bf16x8 af0 = *(const bf16x8*)&As[buf][wr*64 + mi*16 + l15][c0];
      bf16x8 af1 = *(const bf16x8*)&As[buf][wr*64 + mi*16 + l15][c1];
      #pragma unroll
      for (int ni = 0; ni < 4; ++ni){
        acc[mi][ni] = __builtin_amdgcn_mfma_f32_16x16x32_bf16(af0, bf[ni][0], acc[mi][ni], 0,0,0);
        acc[mi][ni] = __builtin_amdgcn_mfma_f32_16x16x32_bf16(af1, bf[ni][1], acc[mi][ni], 0,0,0);
      }
    }
  }
  #pragma unroll
  for (int mi = 0; mi < 4; ++mi){
    int row = m0 + wr*64 + mi*16 + lg*4;
    #pragma unroll
    for (int ni = 0; ni < 4; ++ni){
      int col = n0 + wc*64 + ni*16 + l15;
      float bv_ = bias[col];
      #pragma unroll
      for (int r = 0; r < 4; ++r){
        float val = acc[mi][ni][r] + bv_;
        if (OUT_BF16) ((unsigned short*)Cout)[(size_t)(row + r)*N + col] = f2bf(val);
        else          ((float*)Cout)[(size_t)(row + r)*N + col] = val;
      }
    }
  }
}

// ---- RoPE + rank contraction: build Q,K,V (B,H,S,D) bf16 from bf16 proj.
// Q folds 1/sqrt(64)/ln2 so attention can use exp2. ----
__global__ __launch_bounds__(256) void qkv_kernel(const unsigned short* __restrict__ proj,
    const float* __restrict__ cosT, const float* __restrict__ sinT,
    unsigned short* __restrict__ Q, unsigned short* __restrict__ K,
    unsigned short* __restrict__ V){
  int token = blockIdx.x; int b = token >> 11; int s = token & 2047;
  const unsigned short* row = proj + (size_t)token*NPROJP;
  __shared__ float aq[96], ak[32], av[32], bq[QR][HD], bk[KVR][HD], bv[KVR][HD];
  int t = threadIdx.x;
  if (t < 100){                              // 100 us8 chunks = 800 elems
    us8 v = *(const us8*)(row + t*8);
    int base = t*8;
    float* dst;
    if (base < 96)       dst = &aq[base];
    else if (base < 128) dst = &ak[base-96];
    else if (base < 160) dst = &av[base-128];
    else if (base < 544) dst = &bq[0][0] + (base-160);
    else if (base < 672) dst = &bk[0][0] + (base-544);
    else                 dst = &bv[0][0] + (base-672);
    #pragma unroll
    for (int j = 0; j < 8; ++j) dst[j] = bf2f(v[j]);
  }
  __syncthreads();
  {
    if (t < 192){
      int r = t >> 5, i = t & 31;
      float c = cosT[s*32+i], sn = sinT[s*32+i];
      float x1 = bq[r][2*i], x2 = bq[r][2*i+1];
      bq[r][2*i]   = x1*c - x2*sn;
      bq[r][2*i+1] = x1*sn + x2*c;
    } else {
      int r = (t-192) >> 5, i = t & 31;
      float c = cosT[s*32+i], sn = sinT[s*32+i];
      float x1 = bk[r][2*i], x2 = bk[r][2*i+1];
      bk[r][2*i]   = x1*c - x2*sn;
      bk[r][2*i+1] = x1*sn + x2*c;
    }
  }
  __syncthreads();
  int h = t >> 4; int dbase = (t & 15)*4;
  float qv[4] = {}, kv[4] = {}, vv[4] = {};
  #pragma unroll
  for (int r = 0; r < QR; ++r){
    float a = aq[h*QR + r];
    #pragma unroll
    for (int j = 0; j < 4; ++j) qv[j] += a * bq[r][dbase+j];
  }
  #pragma unroll
  for (int r = 0; r < KVR; ++r){
    float a1 = ak[h*KVR + r], a2 = av[h*KVR + r];
    #pragma unroll
    for (int j = 0; j < 4; ++j){ kv[j] += a1 * bk[r][dbase+j]; vv[j] += a2 * bv[r][dbase+j]; }
  }
  size_t base = ((size_t)(b*NH + h)*SEQ + s)*HD + dbase;
  const float QS = 0.18033688f;  // 0.125 / ln(2)
  ushort4 qo; qo.x=f2bf(qv[0]*QS); qo.y=f2bf(qv[1]*QS); qo.z=f2bf(qv[2]*QS); qo.w=f2bf(qv[3]*QS);
  ushort4 ko; ko.x=f2bf(kv[0]); ko.y=f2bf(kv[1]); ko.z=f2bf(kv[2]); ko.w=f2bf(kv[3]);
  ushort4 vo; vo.x=f2bf(vv[0]); vo.y=f2bf(vv[1]); vo.z=f2bf(vv[2]); vo.w=f2bf(vv[3]);
  *(ushort4*)(Q+base) = qo;
  *(ushort4*)(K+base) = ko;
  *(ushort4*)(V+base) = vo;
}

// ---- one-shot V transpose: V[bh][s][d] -> VT[bh][d][s] ----
__global__ __launch_bounds__(256) void transpose_v(const unsigned short* __restrict__ V,
    unsigned short* __restrict__ VT){
  __shared__ unsigned short tile[64][66];
  int bh = blockIdx.y; int s0 = blockIdx.x*64;
  int tid = threadIdx.x;
  int r = tid >> 3, c = (tid & 7)*8;
  const unsigned short* src = V + ((size_t)bh*SEQ + s0)*HD;
  *(us8*)&tile[r][c]    = *(const us8*)(src + (size_t)r*HD + c);
  *(us8*)&tile[r+32][c] = *(const us8*)(src + (size_t)(r+32)*HD + c);
  __syncthreads();
  unsigned short* dst = VT + (size_t)bh*HD*SEQ + s0;
  us8 o0, o1;
  #pragma unroll
  for (int j = 0; j < 8; ++j){ o0[j] = tile[c+j][r]; o1[j] = tile[c+j][r+32]; }
  *(us8*)(dst + (size_t)r*SEQ + c)      = o0;
  *(us8*)(dst + (size_t)(r+32)*SEQ + c) = o1;
}

// ---- causal flash attention: no-max softmax, paired q-tiles (33 kv-tiles
// per block, perfect balance), 3-buffer 2-deep glds pipeline, counted vmcnt,
// XOR-swizzled LDS, swapped-operand MFMA (q lane-local), zero in-loop shfls.
__global__ __launch_bounds__(256, 2) void attn_kernel(const unsigned short* __restrict__ Q,
   const unsigned short* __restrict__ K, const unsigned short* __restrict__ VT,
   unsigned short* __restrict__ attnOut){
  __shared__ unsigned short Ks[3][64][64];   // 24 KB
  __shared__ unsigned short Vs[3][64][64];   // 24 KB (transposed: [d][k])
  __shared__ unsigned short Pw[4][16][64];   // 8 KB, per-wave P: [q][k]
  int tid = threadIdx.x, w = tid >> 6, lane = tid & 63;
  int id = blockIdx.x;
  int xcd = id & 7, slot = id >> 3;          // 4 bh per XCD -> K/V L2-resident
  int bh  = xcd*4 + (slot & 3);
  int pi  = slot >> 2;                       // 0..15
  int b = bh >> 4, h = bh & 15;
  const unsigned short* Qp = Q  + (size_t)bh*SEQ*HD;
  const unsigned short* Kp = K  + (size_t)bh*SEQ*HD;
  const unsigned short* Vp = VT + (size_t)bh*HD*SEQ;
  int l15 = lane & 15, lg = lane >> 4;
  int u = lg ^ (l15 & 7);
  int c0 = u*8, c1 = (u^4)*8;                // swizzled frag columns
  int w16 = w*16;
  int srow = lane >> 3;                      // staging row-within-8 (= row&7)
  int scol = ((lane & 7) ^ srow) * 8;        // inverse-swizzled source col
  const unsigned short* Kg = Kp + (size_t)(w16 + srow)*HD + scol;
  const unsigned short* Vg = Vp + (size_t)(w16 + srow)*SEQ + scol;
  int pcolbase = ((l15 & 7) * 8);
  auto STAGE = [&](int tt){
    int sb = tt % 3;
    const unsigned short* kg = Kg + (size_t)tt*64*HD;
    const unsigned short* vg = Vg + tt*64;
    gl16(kg,         &Ks[sb][w16][0]);
    gl16(kg + 512,   &Ks[sb][w16+8][0]);     // +8 rows * 64
    gl16(vg,         &Vs[sb][w16][0]);
    gl16(vg + 16384, &Vs[sb][w16+8][0]);     // +8 rows * SEQ
  };
  for (int seg = 0; seg < 2; ++seg){
    int qblk = seg ? pi : 31 - pi;           // heavy q-tile first
    int ntile = qblk + 1;
    int qrow = qblk*64 + w16 + l15;
    bf16x8 aq0 = *(const bf16x8*)(Qp + (size_t)qrow*HD + lg*8);
    bf16x8 aq1 = *(const bf16x8*)(Qp + (size_t)qrow*HD + 32 + lg*8);
    f32x4 o[4] = {};
    float lsum = 0.f;
    SBAR; __builtin_amdgcn_s_barrier(); SBAR;  // prev seg done reading LDS
    STAGE(0);
    if (ntile > 1) STAGE(1);
    for (int t = 0; t < ntile; ++t){
      int buf = t % 3;
      SBAR; __builtin_amdgcn_s_barrier(); SBAR;    // B1: readers of stage-target done
      if (t + 2 < ntile) STAGE(t + 2);
      if (t + 2 < ntile)      asm volatile("s_waitcnt vmcnt(8)" ::: "memory");
      else if (t + 1 < ntile) asm volatile("s_waitcnt vmcnt(4)" ::: "memory");
      else                    asm volatile("s_waitcnt vmcnt(0)" ::: "memory");
      SBAR;
      __builtin_amdgcn_s_barrier(); SBAR;          // B2: tile-t data landed
      // QK^T swapped: sf[f] = S[k = f*16 + lg*4 + r][q = l15]
      f32x4 sf[4];
      #pragma unroll
      for (int f = 0; f < 4; ++f){
        f32x4 z = {};
        bf16x8 kf0 = *(const bf16x8*)&Ks[buf][f*16 + l15][c0];
        bf16x8 kf1 = *(const bf16x8*)&Ks[buf][f*16 + l15][c1];
        z = __builtin_amdgcn_mfma_f32_16x16x32_bf16(kf0, aq0, z, 0,0,0);
        sf[f] = __builtin_amdgcn_mfma_f32_16x16x32_bf16(kf1, aq1, z, 0,0,0);
      }
      if (t == qblk){                        // diagonal tile: mask k > q
        int qloc = w16 + l15;
        #pragma unroll
        for (int f = 0; f < 4; ++f)
          #pragma unroll
          for (int r = 0; r < 4; ++r)
            sf[f][r] = (f*16 + lg*4 + r) <= qloc ? sf[f][r] : -1e30f;
      }
      // no-max softmax: p = exp2(s) directly (scores bounded ~|5|)
      float rs = 0.f;
      ushort4 pu[4];
      #pragma unroll
      for (int f = 0; f < 4; ++f){
        float e0 = exp2f(sf[f][0]), e1 = exp2f(sf[f][1]);
        float e2 = exp2f(sf[f][2]), e3 = exp2f(sf[f][3]);
        rs += (e0 + e1) + (e2 + e3);
        pu[f].x = bfr(e0); pu[f].y = bfr(e1); pu[f].z = bfr(e2); pu[f].w = bfr(e3);
      }
      lsum += rs;
      #pragma unroll
      for (int f = 0; f < 4; ++f)
        *(ushort4*)&Pw[w][l15][(f*16 + lg*4) ^ pcolbase] = pu[f];
      bf16x8 pf0 = *(const bf16x8*)&Pw[w][l15][c0];
      bf16x8 pf1 = *(const bf16x8*)&Pw[w][l15][c1];
      #pragma unroll
      for (int nd = 0; nd < 4; ++nd){
        bf16x8 vf0 = *(const bf16x8*)&Vs[buf][nd*16 + l15][c0];
        bf16x8 vf1 = *(const bf16x8*)&Vs[buf][nd*16 + l15][c1];
        o[nd] = __builtin_amdgcn_mfma_f32_16x16x32_bf16(vf0, pf0, o[nd], 0,0,0);
        o[nd] = __builtin_amdgcn_mfma_f32_16x16x32_bf16(vf1, pf1, o[nd], 0,0,0);
      }
    }
    // row-sum across the 4 lg-lanes (once per seg), then write O[d][q]
    lsum += __shfl_xor(lsum, 16);
    lsum += __shfl_xor(lsum, 32);
    float inv = 1.0f / lsum;
    #pragma unroll
    for (int nd = 0; nd < 4; ++nd){
      ushort4 ov;
      ov.x = bfr(o[nd][0]*inv); ov.y = bfr(o[nd][1]*inv);
      ov.z = bfr(o[nd][2]*inv); ov.w = bfr(o[nd][3]*inv);
      *(ushort4*)(attnOut + ((size_t)b*SEQ + qrow)*DM + h*HD + nd*16 + lg*4) = ov;
    }
  }
}

extern "C" void kernel_launch(void* const* d_in, const int* in_sizes, int n_in,
                              void* d_out, int out_size, void* d_ws, size_t ws_size,
                              hipStream_t stream){
  const float* x   = (const float*)d_in[0];
  const float* Waq = (const float*)d_in[1];
  const float* baq = (const float*)d_in[2];
  const float* Wbq = (const float*)d_in[3];
  const float* bbq = (const float*)d_in[4];
  const float* Wak = (const float*)d_in[5];
  const float* bak = (const float*)d_in[6];
  const float* Wbk = (const float*)d_in[7];
  const float* bbk = (const float*)d_in[8];
  const float* Wav = (const float*)d_in[9];
  const float* bav = (const float*)d_in[10];
  const float* Wbv = (const float*)d_in[11];
  const float* bbv = (const float*)d_in[12];
  const float* Wo  = (const float*)d_in[13];
  const float* bo  = (const float*)d_in[14];
  const float* cosT= (const float*)d_in[15];
  const float* sinT= (const float*)d_in[16];
  float* out = (float*)d_out;

  char* ws = (char*)d_ws;
  // xb reused as VTb after gemm1 consumes it
  unsigned short* xb    = (unsigned short*)(ws + 0);          // 8.4 MB
  unsigned short* VTb   = (unsigned short*)(ws + 0);          // reuse of xb
  unsigned short* Wob   = (unsigned short*)(ws + 8388608);    // 2.1 MB
  unsigned short* Wcat  = (unsigned short*)(ws + 10485760);   // 896x1024x2 = 1.84 MB
  float*          bcat  = (float*)(ws + 12320768);            // 3.6 KB
  unsigned short* projb = (unsigned short*)(ws + 12324352);   // 4096x896x2 = 7.34 MB
  unsigned short* Qb    = (unsigned short*)(ws + 19668992);   // 8.4 MB
  unsigned short* Kb    = (unsigned short*)(ws + 28057600);   // 8.4 MB
  unsigned short* Vb    = (unsigned short*)(ws + 36446208);   // 8.4 MB
  unsigned short* attnB = (unsigned short*)(ws + 44834816);   // 8.4 MB

  cast_kernel<<<4096, 256, 0, stream>>>(x, xb, 1048576);
  cast_kernel<<<1024, 256, 0, stream>>>(Wo, Wob, 262144);
  build_wcat<<<NPROJP, 256, 0, stream>>>(Waq, Wak, Wav, Wbq, Wbk, Wbv,
                                         baq, bak, bav, bbq, bbk, bbv, Wcat, bcat);
  gemm128<1><<<dim3(32,7), 256, 0, stream>>>(xb, Wcat, bcat, projb, NTOK, NPROJP, DM);
  qkv_kernel<<<4096, 256, 0, stream>>>(projb, cosT, sinT, Qb, Kb, Vb);
  transpose_v<<<dim3(32,32), 256, 0, stream>>>(Vb, VTb);
  attn_kernel<<<512, 256, 0, stream>>>(Qb, Kb, VTb, attnB);
  gemm128<0><<<dim3(32,8), 256, 0, stream>>>(attnB, Wob, bo, out, NTOK, DM, DM);
}

// Round 7
// 105.571 us; speedup vs baseline: 2.7904x; 1.0076x over previous
//
#include <hip/hip_runtime.h>
#include <stdint.h>

#define BATCH 2
#define SEQ 2048
#define DM 1024
#define NH 16
#define HD 64
#define QR 6
#define KVR 2
#define NTOK (BATCH*SEQ)
#define NPROJ 832    // live projection outputs
#define NPROJP 896   // padded to 7*128 for 128-col GEMM tiles

typedef __bf16 bf16x8 __attribute__((ext_vector_type(8)));
typedef float f32x4 __attribute__((ext_vector_type(4)));
typedef unsigned short us8 __attribute__((ext_vector_type(8)));

__device__ inline unsigned short f2bf(float f){
  union { float f; unsigned int u; } v; v.f = f;
  unsigned int r = (v.u + 0x7fffu + ((v.u >> 16) & 1u)) >> 16;
  return (unsigned short)r;
}
__device__ __forceinline__ unsigned short bfr(float f){
  __bf16 h = (__bf16)f;
  return *(unsigned short*)&h;
}
__device__ __forceinline__ float bf2f(unsigned short u){
  union { unsigned int i; float f; } v; v.i = ((unsigned int)u) << 16; return v.f;
}
// async global->LDS, 16B per lane; dest = wave-uniform base + lane*16
__device__ __forceinline__ void gl16(const void* g, void* l){
  __builtin_amdgcn_global_load_lds(
      (const __attribute__((address_space(1))) void*)g,
      (__attribute__((address_space(3))) void*)l, 16, 0, 0);
}

// ---- cast f32 -> bf16, 4 elems/thread ----
__global__ void cast_kernel(const float* __restrict__ in, unsigned short* __restrict__ out, int n4){
  int i = blockIdx.x*blockDim.x + threadIdx.x;
  if (i >= n4) return;
  float4 v = ((const float4*)in)[i];
  ushort4 o; o.x = f2bf(v.x); o.y = f2bf(v.y); o.z = f2bf(v.z); o.w = f2bf(v.w);
  ((ushort4*)out)[i] = o;
}

// ---- build concatenated weight (896x1024 bf16, zero-padded) + bias ----
__global__ void build_wcat(const float* __restrict__ Waq, const float* __restrict__ Wak,
                           const float* __restrict__ Wav, const float* __restrict__ Wbq,
                           const float* __restrict__ Wbk, const float* __restrict__ Wbv,
                           const float* __restrict__ baq, const float* __restrict__ bak,
                           const float* __restrict__ bav, const float* __restrict__ bbq,
                           const float* __restrict__ bbk, const float* __restrict__ bbv,
                           unsigned short* __restrict__ Wcat, float* __restrict__ bcat){
  int n = blockIdx.x; int t = threadIdx.x;
  const float* src = nullptr; float bv_ = 0.f;
  if (n < 96)       { src = Waq + (size_t)n*DM;        bv_ = baq[n]; }
  else if (n < 128) { src = Wak + (size_t)(n-96)*DM;   bv_ = bak[n-96]; }
  else if (n < 160) { src = Wav + (size_t)(n-128)*DM;  bv_ = bav[n-128]; }
  else if (n < 544) { src = Wbq + (size_t)(n-160)*DM;  bv_ = bbq[n-160]; }
  else if (n < 672) { src = Wbk + (size_t)(n-544)*DM;  bv_ = bbk[n-544]; }
  else if (n < 800) { src = Wbv + (size_t)(n-672)*DM;  bv_ = bbv[n-672]; }
  unsigned short* dst = Wcat + (size_t)n*DM;
  if (src){
    float4 v = ((const float4*)src)[t];
    ushort4 o; o.x = f2bf(v.x); o.y = f2bf(v.y); o.z = f2bf(v.z); o.w = f2bf(v.w);
    ((ushort4*)dst)[t] = o;
  } else {
    ushort4 z = {0,0,0,0};
    ((ushort4*)dst)[t] = z;
  }
  if (t == 0) bcat[n] = bv_;
}

// ---- 64x128-tile NT bf16 GEMM: C[M,N] = A[M,K]*Bw[N,K]^T + bias.
// 4 waves as 2x2 (each 32x64), BK=64, 2-buffer glds, XOR-swizzled LDS.
// grid: x = n-tile (n-fastest so B stays L2-hot per m-group), y = m-tile.
template<int OUT_BF16>
__global__ __launch_bounds__(256, 2) void gemm64(const unsigned short* __restrict__ A,
    const unsigned short* __restrict__ Bw, const float* __restrict__ bias,
    void* __restrict__ Cout, int M, int N, int K){
  __shared__ unsigned short As[2][64][64];    // 16 KB
  __shared__ unsigned short Bs[2][128][64];   // 32 KB
  int tid = threadIdx.x, w = tid >> 6, lane = tid & 63;
  int wr = w >> 1, wc = w & 1;
  int n0 = blockIdx.x*128, m0 = blockIdx.y*64;
  int l15 = lane & 15, lg = lane >> 4;
  int u = lg ^ (l15 & 7);
  int c0 = u*8, c1 = (u^4)*8;
  int srow = (lane >> 3);                    // = row&7
  int scol = ((lane & 7) ^ srow) * 8;        // inverse-swizzled source col
  const unsigned short* Ag = A  + (size_t)(m0 + w*16 + srow)*K + scol;
  const unsigned short* Bg = Bw + (size_t)(n0 + w*32 + srow)*K + scol;
  size_t K8 = (size_t)8*K;
  f32x4 acc[2][4] = {};
  int nsteps = K >> 6;
  auto STAGE = [&](int ss){
    int sb = ss & 1;
    const unsigned short* An = Ag + ss*64;
    const unsigned short* Bn = Bg + ss*64;
    gl16(An,      &As[sb][w*16][0]);
    gl16(An + K8, &As[sb][w*16 + 8][0]);
    #pragma unroll
    for (int j = 0; j < 4; ++j)
      gl16(Bn + (size_t)j*K8, &Bs[sb][w*32 + j*8][0]);
  };
  STAGE(0);
  for (int s = 0; s < nsteps; ++s){
    int buf = s & 1;
    __syncthreads();                         // stage(s) landed; buf free of readers
    if (s + 1 < nsteps) STAGE(s + 1);
    bf16x8 bf[4][2];
    #pragma unroll
    for (int ni = 0; ni < 4; ++ni){
      bf[ni][0] = *(const bf16x8*)&Bs[buf][wc*64 + ni*16 + l15][c0];
      bf[ni][1] = *(const bf16x8*)&Bs[buf][wc*64 + ni*16 + l15][c1];
    }
    #pragma unroll
    for (int mi = 0; mi < 2; ++mi){
      bf16x8 af0 = *(const bf16x8*)&As[buf][wr*32 + mi*16 + l15][c0];
      bf16x8 af1 = *(const bf16x8*)&As[buf][wr*32 + mi*16 + l15][c1];
      #pragma unroll
      for (int ni = 0; ni < 4; ++ni){
        acc[mi][ni] = __builtin_amdgcn_mfma_f32_16x16x32_bf16(af0, bf[ni][0], acc[mi][ni], 0,0,0);
        acc[mi][ni] = __builtin_amdgcn_mfma_f32_16x16x32_bf16(af1, bf[ni][1], acc[mi][ni], 0,0,0);
      }
    }
  }
  #pragma unroll
  for (int mi = 0; mi < 2; ++mi){
    int row = m0 + wr*32 + mi*16 + lg*4;
    #pragma unroll
    for (int ni = 0; ni < 4; ++ni){
      int col = n0 + wc*64 + ni*16 + l15;
      float bv_ = bias[col];
      #pragma unroll
      for (int r = 0; r < 4; ++r){
        float val = acc[mi][ni][r] + bv_;
        if (OUT_BF16) ((unsigned short*)Cout)[(size_t)(row + r)*N + col] = f2bf(val);
        else          ((float*)Cout)[(size_t)(row + r)*N + col] = val;
      }
    }
  }
}

// ---- RoPE + rank contraction: build Q,K,V (B,H,S,D) bf16 from bf16 proj.
// Q folds 1/sqrt(64)/ln2 so attention can use exp2. ----
__global__ __launch_bounds__(256) void qkv_kernel(const unsigned short* __restrict__ proj,
    const float* __restrict__ cosT, const float* __restrict__ sinT,
    unsigned short* __restrict__ Q, unsigned short* __restrict__ K,
    unsigned short* __restrict__ V){
  int token = blockIdx.x; int b = token >> 11; int s = token & 2047;
  const unsigned short* row = proj + (size_t)token*NPROJP;
  __shared__ float aq[96], ak[32], av[32], bq[QR][HD], bk[KVR][HD], bv[KVR][HD];
  int t = threadIdx.x;
  if (t < 100){                              // 100 us8 chunks = 800 elems
    us8 v = *(const us8*)(row + t*8);
    int base = t*8;
    float* dst;
    if (base < 96)       dst = &aq[base];
    else if (base < 128) dst = &ak[base-96];
    else if (base < 160) dst = &av[base-128];
    else if (base < 544) dst = &bq[0][0] + (base-160);
    else if (base < 672) dst = &bk[0][0] + (base-544);
    else                 dst = &bv[0][0] + (base-672);
    #pragma unroll
    for (int j = 0; j < 8; ++j) dst[j] = bf2f(v[j]);
  }
  __syncthreads();
  {
    if (t < 192){
      int r = t >> 5, i = t & 31;
      float c = cosT[s*32+i], sn = sinT[s*32+i];
      float x1 = bq[r][2*i], x2 = bq[r][2*i+1];
      bq[r][2*i]   = x1*c - x2*sn;
      bq[r][2*i+1] = x1*sn + x2*c;
    } else {
      int r = (t-192) >> 5, i = t & 31;
      float c = cosT[s*32+i], sn = sinT[s*32+i];
      float x1 = bk[r][2*i], x2 = bk[r][2*i+1];
      bk[r][2*i]   = x1*c - x2*sn;
      bk[r][2*i+1] = x1*sn + x2*c;
    }
  }
  __syncthreads();
  int h = t >> 4; int dbase = (t & 15)*4;
  float qv[4] = {}, kv[4] = {}, vv[4] = {};
  #pragma unroll
  for (int r = 0; r < QR; ++r){
    float a = aq[h*QR + r];
    #pragma unroll
    for (int j = 0; j < 4; ++j) qv[j] += a * bq[r][dbase+j];
  }
  #pragma unroll
  for (int r = 0; r < KVR; ++r){
    float a1 = ak[h*KVR + r], a2 = av[h*KVR + r];
    #pragma unroll
    for (int j = 0; j < 4; ++j){ kv[j] += a1 * bk[r][dbase+j]; vv[j] += a2 * bv[r][dbase+j]; }
  }
  size_t base = ((size_t)(b*NH + h)*SEQ + s)*HD + dbase;
  const float QS = 0.18033688f;  // 0.125 / ln(2)
  ushort4 qo; qo.x=f2bf(qv[0]*QS); qo.y=f2bf(qv[1]*QS); qo.z=f2bf(qv[2]*QS); qo.w=f2bf(qv[3]*QS);
  ushort4 ko; ko.x=f2bf(kv[0]); ko.y=f2bf(kv[1]); ko.z=f2bf(kv[2]); ko.w=f2bf(kv[3]);
  ushort4 vo; vo.x=f2bf(vv[0]); vo.y=f2bf(vv[1]); vo.z=f2bf(vv[2]); vo.w=f2bf(vv[3]);
  *(ushort4*)(Q+base) = qo;
  *(ushort4*)(K+base) = ko;
  *(ushort4*)(V+base) = vo;
}

// ---- one-shot V transpose: V[bh][s][d] -> VT[bh][d][s] ----
__global__ __launch_bounds__(256) void transpose_v(const unsigned short* __restrict__ V,
    unsigned short* __restrict__ VT){
  __shared__ unsigned short tile[64][66];
  int bh = blockIdx.y; int s0 = blockIdx.x*64;
  int tid = threadIdx.x;
  int r = tid >> 3, c = (tid & 7)*8;
  const unsigned short* src = V + ((size_t)bh*SEQ + s0)*HD;
  *(us8*)&tile[r][c]    = *(const us8*)(src + (size_t)r*HD + c);
  *(us8*)&tile[r+32][c] = *(const us8*)(src + (size_t)(r+32)*HD + c);
  __syncthreads();
  unsigned short* dst = VT + (size_t)bh*HD*SEQ + s0;
  us8 o0, o1;
  #pragma unroll
  for (int j = 0; j < 8; ++j){ o0[j] = tile[c+j][r]; o1[j] = tile[c+j][r+32]; }
  *(us8*)(dst + (size_t)r*SEQ + c)      = o0;
  *(us8*)(dst + (size_t)(r+32)*SEQ + c) = o1;
}

// ---- causal flash attention: no-max softmax, 1024 independent blocks
// (4 waves, 64 q-rows), 2-buffer glds, XOR-swizzled LDS, swapped-operand
// MFMA (q lane-local), zero in-loop shfls. LDS = 40 KB -> 4 blocks/CU;
// co-resident qblk mapping makes each CU's 4 blocks sum to 66 kv-tiles.
__global__ __launch_bounds__(256, 4) void attn_kernel(const unsigned short* __restrict__ Q,
   const unsigned short* __restrict__ K, const unsigned short* __restrict__ VT,
   unsigned short* __restrict__ attnOut){
  __shared__ unsigned short Ks[2][64][64];   // 16 KB
  __shared__ unsigned short Vs[2][64][64];   // 16 KB (transposed: [d][k])
  __shared__ unsigned short Pw[4][16][64];   // 8 KB, per-wave P: [q][k]
  int tid = threadIdx.x, w = tid >> 6, lane = tid & 63;
  int id = blockIdx.x;
  int bh = id & 31;                          // xcd = bh&7: 4 bh per XCD L2
  int rr = id >> 5, g = rr >> 3, j = rr & 7;
  int qblk = g*8 + ((g & 1) ? (7 - j) : j);  // co-resident sets sum to mean
  int b = bh >> 4, h = bh & 15;
  const unsigned short* Qp = Q  + (size_t)bh*SEQ*HD;
  const unsigned short* Kp = K  + (size_t)bh*SEQ*HD;
  const unsigned short* Vp = VT + (size_t)bh*HD*SEQ;
  int l15 = lane & 15, lg = lane >> 4;
  int u = lg ^ (l15 & 7);
  int c0 = u*8, c1 = (u^4)*8;                // swizzled frag columns
  int w16 = w*16;
  int srow = lane >> 3;                      // staging row-within-8 (= row&7)
  int scol = ((lane & 7) ^ srow) * 8;        // inverse-swizzled source col
  const unsigned short* Kg = Kp + (size_t)(w16 + srow)*HD + scol;
  const unsigned short* Vg = Vp + (size_t)(w16 + srow)*SEQ + scol;
  int pcolbase = ((l15 & 7) * 8);
  auto STAGE = [&](int tt){
    int sb = tt & 1;
    const unsigned short* kg = Kg + (size_t)tt*64*HD;
    const unsigned short* vg = Vg + tt*64;
    gl16(kg,         &Ks[sb][w16][0]);
    gl16(kg + 512,   &Ks[sb][w16+8][0]);     // +8 rows * 64
    gl16(vg,         &Vs[sb][w16][0]);
    gl16(vg + 16384, &Vs[sb][w16+8][0]);     // +8 rows * SEQ
  };
  int ntile = qblk + 1;
  int qrow = qblk*64 + w16 + l15;
  bf16x8 aq0 = *(const bf16x8*)(Qp + (size_t)qrow*HD + lg*8);
  bf16x8 aq1 = *(const bf16x8*)(Qp + (size_t)qrow*HD + 32 + lg*8);
  f32x4 o[4] = {};
  float lsum = 0.f;
  STAGE(0);
  for (int t = 0; t < ntile; ++t){
    int buf = t & 1;
    __syncthreads();                         // stage(t) landed; buf readers done
    if (t + 1 < ntile) STAGE(t + 1);
    // QK^T swapped: sf[f] = S[k = f*16 + lg*4 + r][q = l15]
    f32x4 sf[4];
    #pragma unroll
    for (int f = 0; f < 4; ++f){
      f32x4 z = {};
      bf16x8 kf0 = *(const bf16x8*)&Ks[buf][f*16 + l15][c0];
      bf16x8 kf1 = *(const bf16x8*)&Ks[buf][f*16 + l15][c1];
      z = __builtin_amdgcn_mfma_f32_16x16x32_bf16(kf0, aq0, z, 0,0,0);
      sf[f] = __builtin_amdgcn_mfma_f32_16x16x32_bf16(kf1, aq1, z, 0,0,0);
    }
    if (t == qblk){                          // diagonal tile: mask k > q
      int qloc = w16 + l15;
      #pragma unroll
      for (int f = 0; f < 4; ++f)
        #pragma unroll
        for (int r = 0; r < 4; ++r)
          sf[f][r] = (f*16 + lg*4 + r) <= qloc ? sf[f][r] : -1e30f;
    }
    // no-max softmax: p = exp2(s) directly (scores bounded ~|5|)
    float rs = 0.f;
    ushort4 pu[4];
    #pragma unroll
    for (int f = 0; f < 4; ++f){
      float e0 = exp2f(sf[f][0]), e1 = exp2f(sf[f][1]);
      float e2 = exp2f(sf[f][2]), e3 = exp2f(sf[f][3]);
      rs += (e0 + e1) + (e2 + e3);
      pu[f].x = bfr(e0); pu[f].y = bfr(e1); pu[f].z = bfr(e2); pu[f].w = bfr(e3);
    }
    lsum += rs;
    #pragma unroll
    for (int f = 0; f < 4; ++f)
      *(ushort4*)&Pw[w][l15][(f*16 + lg*4) ^ pcolbase] = pu[f];
    bf16x8 pf0 = *(const bf16x8*)&Pw[w][l15][c0];
    bf16x8 pf1 = *(const bf16x8*)&Pw[w][l15][c1];
    #pragma unroll
    for (int nd = 0; nd < 4; ++nd){
      bf16x8 vf0 = *(const bf16x8*)&Vs[buf][nd*16 + l15][c0];
      bf16x8 vf1 = *(const bf16x8*)&Vs[buf][nd*16 + l15][c1];
      o[nd] = __builtin_amdgcn_mfma_f32_16x16x32_bf16(vf0, pf0, o[nd], 0,0,0);
      o[nd] = __builtin_amdgcn_mfma_f32_16x16x32_bf16(vf1, pf1, o[nd], 0,0,0);
    }
  }
  // row-sum across the 4 lg-lanes (once), then write O[d][q]
  lsum += __shfl_xor(lsum, 16);
  lsum += __shfl_xor(lsum, 32);
  float inv = 1.0f / lsum;
  #pragma unroll
  for (int nd = 0; nd < 4; ++nd){
    ushort4 ov;
    ov.x = bfr(o[nd][0]*inv); ov.y = bfr(o[nd][1]*inv);
    ov.z = bfr(o[nd][2]*inv); ov.w = bfr(o[nd][3]*inv);
    *(ushort4*)(attnOut + ((size_t)b*SEQ + qrow)*DM + h*HD + nd*16 + lg*4) = ov;
  }
}

extern "C" void kernel_launch(void* const* d_in, const int* in_sizes, int n_in,
                              void* d_out, int out_size, void* d_ws, size_t ws_size,
                              hipStream_t stream){
  const float* x   = (const float*)d_in[0];
  const float* Waq = (const float*)d_in[1];
  const float* baq = (const float*)d_in[2];
  const float* Wbq = (const float*)d_in[3];
  const float* bbq = (const float*)d_in[4];
  const float* Wak = (const float*)d_in[5];
  const float* bak = (const float*)d_in[6];
  const float* Wbk = (const float*)d_in[7];
  const float* bbk = (const float*)d_in[8];
  const float* Wav = (const float*)d_in[9];
  const float* bav = (const float*)d_in[10];
  const float* Wbv = (const float*)d_in[11];
  const float* bbv = (const float*)d_in[12];
  const float* Wo  = (const float*)d_in[13];
  const float* bo  = (const float*)d_in[14];
  const float* cosT= (const float*)d_in[15];
  const float* sinT= (const float*)d_in[16];
  float* out = (float*)d_out;

  char* ws = (char*)d_ws;
  // xb reused as VTb after gemm1 consumes it
  unsigned short* xb    = (unsigned short*)(ws + 0);          // 8.4 MB
  unsigned short* VTb   = (unsigned short*)(ws + 0);          // reuse of xb
  unsigned short* Wob   = (unsigned short*)(ws + 8388608);    // 2.1 MB
  unsigned short* Wcat  = (unsigned short*)(ws + 10485760);   // 896x1024x2 = 1.84 MB
  float*          bcat  = (float*)(ws + 12320768);            // 3.6 KB
  unsigned short* projb = (unsigned short*)(ws + 12324352);   // 4096x896x2 = 7.34 MB
  unsigned short* Qb    = (unsigned short*)(ws + 19668992);   // 8.4 MB
  unsigned short* Kb    = (unsigned short*)(ws + 28057600);   // 8.4 MB
  unsigned short* Vb    = (unsigned short*)(ws + 36446208);   // 8.4 MB
  unsigned short* attnB = (unsigned short*)(ws + 44834816);   // 8.4 MB

  cast_kernel<<<4096, 256, 0, stream>>>(x, xb, 1048576);
  cast_kernel<<<1024, 256, 0, stream>>>(Wo, Wob, 262144);
  build_wcat<<<NPROJP, 256, 0, stream>>>(Waq, Wak, Wav, Wbq, Wbk, Wbv,
                                         baq, bak, bav, bbq, bbk, bbv, Wcat, bcat);
  gemm64<1><<<dim3(7, 64), 256, 0, stream>>>(xb, Wcat, bcat, projb, NTOK, NPROJP, DM);
  qkv_kernel<<<4096, 256, 0, stream>>>(projb, cosT, sinT, Qb, Kb, Vb);
  transpose_v<<<dim3(32,32), 256, 0, stream>>>(Vb, VTb);
  attn_kernel<<<1024, 256, 0, stream>>>(Qb, Kb, VTb, attnB);
  gemm64<0><<<dim3(8, 64), 256, 0, stream>>>(attnB, Wob, bo, out, NTOK, DM, DM);
}

// Round 8
// 104.554 us; speedup vs baseline: 2.8175x; 1.0097x over previous
//
#include <hip/hip_runtime.h>
#include <stdint.h>

#define BATCH 2
#define SEQ 2048
#define DM 1024
#define NH 16
#define HD 64
#define QR 6
#define KVR 2
#define NTOK (BATCH*SEQ)
#define NPROJ 832    // live projection outputs
#define NPROJP 896   // padded to 7*128 for 128-col GEMM tiles

typedef __bf16 bf16x8 __attribute__((ext_vector_type(8)));
typedef float f32x4 __attribute__((ext_vector_type(4)));
typedef unsigned short us8 __attribute__((ext_vector_type(8)));

__device__ inline unsigned short f2bf(float f){
  union { float f; unsigned int u; } v; v.f = f;
  unsigned int r = (v.u + 0x7fffu + ((v.u >> 16) & 1u)) >> 16;
  return (unsigned short)r;
}
__device__ __forceinline__ unsigned short bfr(float f){
  __bf16 h = (__bf16)f;
  return *(unsigned short*)&h;
}
__device__ __forceinline__ float bf2f(unsigned short u){
  union { unsigned int i; float f; } v; v.i = ((unsigned int)u) << 16; return v.f;
}
// async global->LDS, 16B per lane; dest = wave-uniform base + lane*16
__device__ __forceinline__ void gl16(const void* g, void* l){
  __builtin_amdgcn_global_load_lds(
      (const __attribute__((address_space(1))) void*)g,
      (__attribute__((address_space(3))) void*)l, 16, 0, 0);
}

// ---- cast f32 -> bf16, 4 elems/thread ----
__global__ void cast_kernel(const float* __restrict__ in, unsigned short* __restrict__ out, int n4){
  int i = blockIdx.x*blockDim.x + threadIdx.x;
  if (i >= n4) return;
  float4 v = ((const float4*)in)[i];
  ushort4 o; o.x = f2bf(v.x); o.y = f2bf(v.y); o.z = f2bf(v.z); o.w = f2bf(v.w);
  ((ushort4*)out)[i] = o;
}

// ---- prep: blocks [0,896) build Wcat row; blocks [896,1920) cast Wo ----
__global__ void prep_kernel(const float* __restrict__ Waq, const float* __restrict__ Wak,
                            const float* __restrict__ Wav, const float* __restrict__ Wbq,
                            const float* __restrict__ Wbk, const float* __restrict__ Wbv,
                            const float* __restrict__ baq, const float* __restrict__ bak,
                            const float* __restrict__ bav, const float* __restrict__ bbq,
                            const float* __restrict__ bbk, const float* __restrict__ bbv,
                            unsigned short* __restrict__ Wcat, float* __restrict__ bcat,
                            const float* __restrict__ Wo, unsigned short* __restrict__ Wob){
  int n = blockIdx.x; int t = threadIdx.x;
  if (n >= NPROJP){                          // Wo cast: 1024 blocks x 256 x ushort4
    int i = (n - NPROJP)*256 + t;
    float4 v = ((const float4*)Wo)[i];
    ushort4 o; o.x = f2bf(v.x); o.y = f2bf(v.y); o.z = f2bf(v.z); o.w = f2bf(v.w);
    ((ushort4*)Wob)[i] = o;
    return;
  }
  const float* src = nullptr; float bv_ = 0.f;
  if (n < 96)       { src = Waq + (size_t)n*DM;        bv_ = baq[n]; }
  else if (n < 128) { src = Wak + (size_t)(n-96)*DM;   bv_ = bak[n-96]; }
  else if (n < 160) { src = Wav + (size_t)(n-128)*DM;  bv_ = bav[n-128]; }
  else if (n < 544) { src = Wbq + (size_t)(n-160)*DM;  bv_ = bbq[n-160]; }
  else if (n < 672) { src = Wbk + (size_t)(n-544)*DM;  bv_ = bbk[n-544]; }
  else if (n < 800) { src = Wbv + (size_t)(n-672)*DM;  bv_ = bbv[n-672]; }
  unsigned short* dst = Wcat + (size_t)n*DM;
  if (src){
    float4 v = ((const float4*)src)[t];
    ushort4 o; o.x = f2bf(v.x); o.y = f2bf(v.y); o.z = f2bf(v.z); o.w = f2bf(v.w);
    ((ushort4*)dst)[t] = o;
  } else {
    ushort4 z = {0,0,0,0};
    ((ushort4*)dst)[t] = z;
  }
  if (t == 0) bcat[n] = bv_;
}

// ---- 64x128-tile NT bf16 GEMM: C[M,N] = A[M,K]*Bw[N,K]^T + bias.
// 4 waves as 2x2 (each 32x64), BK=64, 2-buffer glds, XOR-swizzled LDS.
template<int OUT_BF16>
__global__ __launch_bounds__(256, 2) void gemm64(const unsigned short* __restrict__ A,
    const unsigned short* __restrict__ Bw, const float* __restrict__ bias,
    void* __restrict__ Cout, int M, int N, int K){
  __shared__ unsigned short As[2][64][64];    // 16 KB
  __shared__ unsigned short Bs[2][128][64];   // 32 KB
  int tid = threadIdx.x, w = tid >> 6, lane = tid & 63;
  int wr = w >> 1, wc = w & 1;
  int n0 = blockIdx.x*128, m0 = blockIdx.y*64;
  int l15 = lane & 15, lg = lane >> 4;
  int u = lg ^ (l15 & 7);
  int c0 = u*8, c1 = (u^4)*8;
  int srow = (lane >> 3);                    // = row&7
  int scol = ((lane & 7) ^ srow) * 8;        // inverse-swizzled source col
  const unsigned short* Ag = A  + (size_t)(m0 + w*16 + srow)*K + scol;
  const unsigned short* Bg = Bw + (size_t)(n0 + w*32 + srow)*K + scol;
  size_t K8 = (size_t)8*K;
  f32x4 acc[2][4] = {};
  int nsteps = K >> 6;
  auto STAGE = [&](int ss){
    int sb = ss & 1;
    const unsigned short* An = Ag + ss*64;
    const unsigned short* Bn = Bg + ss*64;
    gl16(An,      &As[sb][w*16][0]);
    gl16(An + K8, &As[sb][w*16 + 8][0]);
    #pragma unroll
    for (int j = 0; j < 4; ++j)
      gl16(Bn + (size_t)j*K8, &Bs[sb][w*32 + j*8][0]);
  };
  STAGE(0);
  for (int s = 0; s < nsteps; ++s){
    int buf = s & 1;
    __syncthreads();                         // stage(s) landed; buf free of readers
    if (s + 1 < nsteps) STAGE(s + 1);
    bf16x8 bf[4][2];
    #pragma unroll
    for (int ni = 0; ni < 4; ++ni){
      bf[ni][0] = *(const bf16x8*)&Bs[buf][wc*64 + ni*16 + l15][c0];
      bf[ni][1] = *(const bf16x8*)&Bs[buf][wc*64 + ni*16 + l15][c1];
    }
    __builtin_amdgcn_s_setprio(1);
    #pragma unroll
    for (int mi = 0; mi < 2; ++mi){
      bf16x8 af0 = *(const bf16x8*)&As[buf][wr*32 + mi*16 + l15][c0];
      bf16x8 af1 = *(const bf16x8*)&As[buf][wr*32 + mi*16 + l15][c1];
      #pragma unroll
      for (int ni = 0; ni < 4; ++ni){
        acc[mi][ni] = __builtin_amdgcn_mfma_f32_16x16x32_bf16(af0, bf[ni][0], acc[mi][ni], 0,0,0);
        acc[mi][ni] = __builtin_amdgcn_mfma_f32_16x16x32_bf16(af1, bf[ni][1], acc[mi][ni], 0,0,0);
      }
    }
    __builtin_amdgcn_s_setprio(0);
  }
  #pragma unroll
  for (int mi = 0; mi < 2; ++mi){
    int row = m0 + wr*32 + mi*16 + lg*4;
    #pragma unroll
    for (int ni = 0; ni < 4; ++ni){
      int col = n0 + wc*64 + ni*16 + l15;
      float bv_ = bias[col];
      #pragma unroll
      for (int r = 0; r < 4; ++r){
        float val = acc[mi][ni][r] + bv_;
        if (OUT_BF16) ((unsigned short*)Cout)[(size_t)(row + r)*N + col] = f2bf(val);
        else          ((float*)Cout)[(size_t)(row + r)*N + col] = val;
      }
    }
  }
}

// ---- qkv8: 8 tokens/block (512 blocks). RoPE + rank contraction from bf16
// proj; writes Q,K row-major and V DIRECTLY TRANSPOSED (VT[bh][d][s]) via an
// LDS retile -- replaces the old qkv + transpose_v pair.
// Q folds 1/sqrt(64)/ln2 so attention can use exp2.
__global__ __launch_bounds__(256) void qkv8_kernel(const unsigned short* __restrict__ proj,
    const float* __restrict__ cosT, const float* __restrict__ sinT,
    unsigned short* __restrict__ Q, unsigned short* __restrict__ K,
    unsigned short* __restrict__ VT){
  __shared__ unsigned short projS[8][800];   // 12.8 KB (bf16)
  __shared__ float rq[QR][HD];               // roped b_q (reused per token)
  __shared__ float rk[KVR][HD];              // roped b_k
  __shared__ unsigned short vt[NH][HD][8];   // 16 KB V^T staging
  int t = threadIdx.x;
  int tok0 = blockIdx.x*8;
  int b = tok0 >> 11;
  int s0 = tok0 & 2047;
  if (t < 100){
    #pragma unroll
    for (int j = 0; j < 8; ++j)
      *(us8*)&projS[j][t*8] = *(const us8*)(proj + (size_t)(tok0+j)*NPROJP + t*8);
  }
  __syncthreads();
  int h = t >> 4, dbase = (t & 15)*4;
  for (int j = 0; j < 8; ++j){
    int s = s0 + j;
    if (t < 192){
      int r = t >> 5, i = t & 31;
      float c = cosT[s*32+i], sn = sinT[s*32+i];
      float x1 = bf2f(projS[j][160 + r*64 + 2*i]);
      float x2 = bf2f(projS[j][160 + r*64 + 2*i + 1]);
      rq[r][2*i]   = x1*c - x2*sn;
      rq[r][2*i+1] = x1*sn + x2*c;
    } else {
      int r = (t-192) >> 5, i = t & 31;
      float c = cosT[s*32+i], sn = sinT[s*32+i];
      float x1 = bf2f(projS[j][544 + r*64 + 2*i]);
      float x2 = bf2f(projS[j][544 + r*64 + 2*i + 1]);
      rk[r][2*i]   = x1*c - x2*sn;
      rk[r][2*i+1] = x1*sn + x2*c;
    }
    __syncthreads();
    float qv[4] = {}, kv[4] = {}, vv[4] = {};
    #pragma unroll
    for (int r = 0; r < QR; ++r){
      float a = bf2f(projS[j][h*QR + r]);
      f32x4 rv = *(const f32x4*)&rq[r][dbase];
      qv[0] += a*rv[0]; qv[1] += a*rv[1]; qv[2] += a*rv[2]; qv[3] += a*rv[3];
    }
    #pragma unroll
    for (int r = 0; r < KVR; ++r){
      float a1 = bf2f(projS[j][96 + h*KVR + r]);
      float a2 = bf2f(projS[j][128 + h*KVR + r]);
      f32x4 rv = *(const f32x4*)&rk[r][dbase];
      kv[0] += a1*rv[0]; kv[1] += a1*rv[1]; kv[2] += a1*rv[2]; kv[3] += a1*rv[3];
      ushort4 bu = *(const ushort4*)&projS[j][672 + r*64 + dbase];
      vv[0] += a2*bf2f(bu.x); vv[1] += a2*bf2f(bu.y);
      vv[2] += a2*bf2f(bu.z); vv[3] += a2*bf2f(bu.w);
    }
    size_t base = ((size_t)(b*NH + h)*SEQ + s)*HD + dbase;
    const float QS = 0.18033688f;  // 0.125 / ln(2)
    ushort4 qo; qo.x=f2bf(qv[0]*QS); qo.y=f2bf(qv[1]*QS); qo.z=f2bf(qv[2]*QS); qo.w=f2bf(qv[3]*QS);
    ushort4 ko; ko.x=f2bf(kv[0]); ko.y=f2bf(kv[1]); ko.z=f2bf(kv[2]); ko.w=f2bf(kv[3]);
    *(ushort4*)(Q+base) = qo;
    *(ushort4*)(K+base) = ko;
    vt[h][dbase  ][j] = f2bf(vv[0]);
    vt[h][dbase+1][j] = f2bf(vv[1]);
    vt[h][dbase+2][j] = f2bf(vv[2]);
    vt[h][dbase+3][j] = f2bf(vv[3]);
    __syncthreads();                         // rq/rk reused next token; vt complete at end
  }
  #pragma unroll
  for (int k = 0; k < 4; ++k){
    int idx = t + k*256;                     // 1024 (h,d) pairs
    int hh = idx >> 6, dd = idx & 63;
    *(us8*)(VT + ((size_t)(b*NH + hh)*HD + dd)*SEQ + s0) = *(const us8*)&vt[hh][dd][0];
  }
}

// ---- causal flash attention: no-max softmax, PAIRED q-tiles (each block does
// q-tiles {31-pi, pi} = 33 kv-tiles, perfect balance by construction),
// 2-buffer glds, XOR-swizzled LDS, swapped-operand MFMA (q lane-local),
// s_setprio around MFMA clusters, zero in-loop shfls. LDS 40 KB.
__global__ __launch_bounds__(256, 4) void attn_kernel(const unsigned short* __restrict__ Q,
   const unsigned short* __restrict__ K, const unsigned short* __restrict__ VT,
   unsigned short* __restrict__ attnOut){
  __shared__ unsigned short Ks[2][64][64];   // 16 KB
  __shared__ unsigned short Vs[2][64][64];   // 16 KB (transposed: [d][k])
  __shared__ unsigned short Pw[4][16][64];   // 8 KB, per-wave P: [q][k]
  int tid = threadIdx.x, w = tid >> 6, lane = tid & 63;
  int id = blockIdx.x;
  int xcd = id & 7, slot = id >> 3;          // 4 bh per XCD -> K/V L2-resident
  int bh  = xcd*4 + (slot & 3);
  int pi  = slot >> 2;                       // 0..15
  int b = bh >> 4, h = bh & 15;
  const unsigned short* Qp = Q  + (size_t)bh*SEQ*HD;
  const unsigned short* Kp = K  + (size_t)bh*SEQ*HD;
  const unsigned short* Vp = VT + (size_t)bh*HD*SEQ;
  int l15 = lane & 15, lg = lane >> 4;
  int u = lg ^ (l15 & 7);
  int c0 = u*8, c1 = (u^4)*8;                // swizzled frag columns
  int w16 = w*16;
  int srow = lane >> 3;                      // staging row-within-8 (= row&7)
  int scol = ((lane & 7) ^ srow) * 8;        // inverse-swizzled source col
  const unsigned short* Kg = Kp + (size_t)(w16 + srow)*HD + scol;
  const unsigned short* Vg = Vp + (size_t)(w16 + srow)*SEQ + scol;
  int pcolbase = ((l15 & 7) * 8);
  auto STAGE = [&](int tt){
    int sb = tt & 1;
    const unsigned short* kg = Kg + (size_t)tt*64*HD;
    const unsigned short* vg = Vg + tt*64;
    gl16(kg,         &Ks[sb][w16][0]);
    gl16(kg + 512,   &Ks[sb][w16+8][0]);     // +8 rows * 64
    gl16(vg,         &Vs[sb][w16][0]);
    gl16(vg + 16384, &Vs[sb][w16+8][0]);     // +8 rows * SEQ
  };
  for (int seg = 0; seg < 2; ++seg){
    int qblk = seg ? pi : 31 - pi;           // heavy q-tile first
    int ntile = qblk + 1;
    int qrow = qblk*64 + w16 + l15;
    bf16x8 aq0 = *(const bf16x8*)(Qp + (size_t)qrow*HD + lg*8);
    bf16x8 aq1 = *(const bf16x8*)(Qp + (size_t)qrow*HD + 32 + lg*8);
    f32x4 o[4] = {};
    float lsum = 0.f;
    __syncthreads();                         // prev seg's readers done with LDS
    STAGE(0);
    for (int t = 0; t < ntile; ++t){
      int buf = t & 1;
      __syncthreads();                       // stage(t) landed; buf readers done
      if (t + 1 < ntile) STAGE(t + 1);
      // QK^T swapped: sf[f] = S[k = f*16 + lg*4 + r][q = l15]
      f32x4 sf[4];
      __builtin_amdgcn_s_setprio(1);
      #pragma unroll
      for (int f = 0; f < 4; ++f){
        f32x4 z = {};
        bf16x8 kf0 = *(const bf16x8*)&Ks[buf][f*16 + l15][c0];
        bf16x8 kf1 = *(const bf16x8*)&Ks[buf][f*16 + l15][c1];
        z = __builtin_amdgcn_mfma_f32_16x16x32_bf16(kf0, aq0, z, 0,0,0);
        sf[f] = __builtin_amdgcn_mfma_f32_16x16x32_bf16(kf1, aq1, z, 0,0,0);
      }
      __builtin_amdgcn_s_setprio(0);
      if (t == qblk){                        // diagonal tile: mask k > q
        int qloc = w16 + l15;
        #pragma unroll
        for (int f = 0; f < 4; ++f)
          #pragma unroll
          for (int r = 0; r < 4; ++r)
            sf[f][r] = (f*16 + lg*4 + r) <= qloc ? sf[f][r] : -1e30f;
      }
      // no-max softmax: p = exp2(s) directly (scores bounded ~|5|)
      float rs = 0.f;
      ushort4 pu[4];
      #pragma unroll
      for (int f = 0; f < 4; ++f){
        float e0 = exp2f(sf[f][0]), e1 = exp2f(sf[f][1]);
        float e2 = exp2f(sf[f][2]), e3 = exp2f(sf[f][3]);
        rs += (e0 + e1) + (e2 + e3);
        pu[f].x = bfr(e0); pu[f].y = bfr(e1); pu[f].z = bfr(e2); pu[f].w = bfr(e3);
      }
      lsum += rs;
      #pragma unroll
      for (int f = 0; f < 4; ++f)
        *(ushort4*)&Pw[w][l15][(f*16 + lg*4) ^ pcolbase] = pu[f];
      bf16x8 pf0 = *(const bf16x8*)&Pw[w][l15][c0];
      bf16x8 pf1 = *(const bf16x8*)&Pw[w][l15][c1];
      __builtin_amdgcn_s_setprio(1);
      #pragma unroll
      for (int nd = 0; nd < 4; ++nd){
        bf16x8 vf0 = *(const bf16x8*)&Vs[buf][nd*16 + l15][c0];
        bf16x8 vf1 = *(const bf16x8*)&Vs[buf][nd*16 + l15][c1];
        o[nd] = __builtin_amdgcn_mfma_f32_16x16x32_bf16(vf0, pf0, o[nd], 0,0,0);
        o[nd] = __builtin_amdgcn_mfma_f32_16x16x32_bf16(vf1, pf1, o[nd], 0,0,0);
      }
      __builtin_amdgcn_s_setprio(0);
    }
    // row-sum across the 4 lg-lanes (once per seg), then write O[d][q]
    lsum += __shfl_xor(lsum, 16);
    lsum += __shfl_xor(lsum, 32);
    float inv = 1.0f / lsum;
    #pragma unroll
    for (int nd = 0; nd < 4; ++nd){
      ushort4 ov;
      ov.x = bfr(o[nd][0]*inv); ov.y = bfr(o[nd][1]*inv);
      ov.z = bfr(o[nd][2]*inv); ov.w = bfr(o[nd][3]*inv);
      *(ushort4*)(attnOut + ((size_t)b*SEQ + qrow)*DM + h*HD + nd*16 + lg*4) = ov;
    }
  }
}

extern "C" void kernel_launch(void* const* d_in, const int* in_sizes, int n_in,
                              void* d_out, int out_size, void* d_ws, size_t ws_size,
                              hipStream_t stream){
  const float* x   = (const float*)d_in[0];
  const float* Waq = (const float*)d_in[1];
  const float* baq = (const float*)d_in[2];
  const float* Wbq = (const float*)d_in[3];
  const float* bbq = (const float*)d_in[4];
  const float* Wak = (const float*)d_in[5];
  const float* bak = (const float*)d_in[6];
  const float* Wbk = (const float*)d_in[7];
  const float* bbk = (const float*)d_in[8];
  const float* Wav = (const float*)d_in[9];
  const float* bav = (const float*)d_in[10];
  const float* Wbv = (const float*)d_in[11];
  const float* bbv = (const float*)d_in[12];
  const float* Wo  = (const float*)d_in[13];
  const float* bo  = (const float*)d_in[14];
  const float* cosT= (const float*)d_in[15];
  const float* sinT= (const float*)d_in[16];
  float* out = (float*)d_out;

  char* ws = (char*)d_ws;
  // xb reused as VTb after gemm1 consumes it
  unsigned short* xb    = (unsigned short*)(ws + 0);          // 8.4 MB
  unsigned short* VTb   = (unsigned short*)(ws + 0);          // reuse of xb
  unsigned short* Wob   = (unsigned short*)(ws + 8388608);    // 2.1 MB
  unsigned short* Wcat  = (unsigned short*)(ws + 10485760);   // 896x1024x2 = 1.84 MB
  float*          bcat  = (float*)(ws + 12320768);            // 3.6 KB
  unsigned short* projb = (unsigned short*)(ws + 12324352);   // 4096x896x2 = 7.34 MB
  unsigned short* Qb    = (unsigned short*)(ws + 19668992);   // 8.4 MB
  unsigned short* Kb    = (unsigned short*)(ws + 28057600);   // 8.4 MB
  unsigned short* attnB = (unsigned short*)(ws + 44834816);   // 8.4 MB

  cast_kernel<<<4096, 256, 0, stream>>>(x, xb, 1048576);
  prep_kernel<<<NPROJP + 1024, 256, 0, stream>>>(Waq, Wak, Wav, Wbq, Wbk, Wbv,
                                                 baq, bak, bav, bbq, bbk, bbv,
                                                 Wcat, bcat, Wo, Wob);
  gemm64<1><<<dim3(7, 64), 256, 0, stream>>>(xb, Wcat, bcat, projb, NTOK, NPROJP, DM);
  qkv8_kernel<<<512, 256, 0, stream>>>(projb, cosT, sinT, Qb, Kb, VTb);
  attn_kernel<<<512, 256, 0, stream>>>(Qb, Kb, VTb, attnB);
  gemm64<0><<<dim3(8, 64), 256, 0, stream>>>(attnB, Wob, bo, out, NTOK, DM, DM);
}